// Round 2
// baseline (160.173 us; speedup 1.0000x reference)
//
#include <hip/hip_runtime.h>
#include <hip/hip_bf16.h>
#include <stdint.h>

typedef __bf16 bf16_t;
typedef __bf16 bf16x8 __attribute__((ext_vector_type(8)));
typedef __bf16 bf16x4 __attribute__((ext_vector_type(4)));
typedef float  f32x4  __attribute__((ext_vector_type(4)));

#define DEV __device__ __forceinline__

static constexpr int NTOK = 2048;
static constexpr int DIM  = 1024;
static constexpr int NH   = 16;
static constexpr int DH   = 64;
static constexpr int QKVN = 3072;

DEV void gload_lds16(const void* g, void* l) {
  __builtin_amdgcn_global_load_lds(
      (__attribute__((address_space(1))) void*)(g),
      (__attribute__((address_space(3))) void*)(l), 16, 0, 0);
}

DEV float bf2f(bf16_t b) { return (float)b; }

// ---------------- LayerNorm + cast to bf16 ----------------
__global__ __launch_bounds__(256) void k_ln(const float* __restrict__ x,
                                            const float* __restrict__ gamma,
                                            const float* __restrict__ beta,
                                            bf16_t* __restrict__ xn) {
  const int row = blockIdx.x;
  const int t = threadIdx.x;
  const float4* x4 = reinterpret_cast<const float4*>(x);
  float4 v = x4[(size_t)row * 256 + t];
  float s  = v.x + v.y + v.z + v.w;
  float s2 = v.x * v.x + v.y * v.y + v.z * v.z + v.w * v.w;
#pragma unroll
  for (int o = 1; o < 64; o <<= 1) {
    s  += __shfl_xor(s, o, 64);
    s2 += __shfl_xor(s2, o, 64);
  }
  __shared__ float red[8];
  const int w = t >> 6, lane = t & 63;
  if (lane == 0) { red[w] = s; red[4 + w] = s2; }
  __syncthreads();
  s  = red[0] + red[1] + red[2] + red[3];
  s2 = red[4] + red[5] + red[6] + red[7];
  const float mu  = s * (1.0f / 1024.0f);
  const float var = s2 * (1.0f / 1024.0f) - mu * mu;
  const float inv = rsqrtf(var + 1e-6f);
  const float4 g = reinterpret_cast<const float4*>(gamma)[t];
  const float4 b = reinterpret_cast<const float4*>(beta)[t];
  bf16x4 o;
  o[0] = (bf16_t)((v.x - mu) * inv * g.x + b.x);
  o[1] = (bf16_t)((v.y - mu) * inv * g.y + b.y);
  o[2] = (bf16_t)((v.z - mu) * inv * g.z + b.z);
  o[3] = (bf16_t)((v.w - mu) * inv * g.w + b.w);
  *reinterpret_cast<bf16x4*>(xn + (size_t)row * DIM + t * 4) = o;
}

// ---------------- transpose + cast fp32 MxN -> bf16 NxM ----------------
__global__ __launch_bounds__(256) void k_tc(const float* __restrict__ src,
                                            bf16_t* __restrict__ dst,
                                            int M, int N) {
  __shared__ float tile[64][65];
  const int c0 = blockIdx.x * 64;
  const int r0 = blockIdx.y * 64;
  const int tx = threadIdx.x & 63;
  const int ty = threadIdx.x >> 6;
#pragma unroll
  for (int i = 0; i < 16; ++i) {
    int r = ty + i * 4;
    tile[r][tx] = src[(size_t)(r0 + r) * N + c0 + tx];
  }
  __syncthreads();
#pragma unroll
  for (int i = 0; i < 16; ++i) {
    int r = ty + i * 4;
    dst[(size_t)(c0 + r) * M + r0 + tx] = (bf16_t)tile[tx][r];
  }
}

// ---------------- GEMM: C[M,N] = A[M,K] * Bt[N,K]^T (+bias), m97 structure ----------------
template <int F32OUT>
__global__ __launch_bounds__(256) void k_gemm_bt(const bf16_t* __restrict__ A,
                                                 const bf16_t* __restrict__ Bt,
                                                 bf16_t* __restrict__ Cb,
                                                 float* __restrict__ Cf,
                                                 const float* __restrict__ bias,
                                                 int M, int N, int K) {
  __shared__ alignas(16) bf16_t As[128 * 32];
  __shared__ alignas(16) bf16_t Bs[128 * 32];
  const int tid = threadIdx.x, lane = tid & 63, w = tid >> 6;
  const int bm = blockIdx.x * 128, bn = blockIdx.y * 128;
  const int wr = (w >> 1) * 64, wc = (w & 1) * 64;
  f32x4 acc[4][4];
#pragma unroll
  for (int i = 0; i < 4; ++i)
#pragma unroll
    for (int j = 0; j < 4; ++j) acc[i][j] = f32x4{0.f, 0.f, 0.f, 0.f};

  const int srow  = lane >> 2;        // 0..15
  const int scol8 = (lane & 3) * 8;   // element offset in K

  for (int kt = 0; kt < K; kt += 32) {
    __syncthreads();
#pragma unroll
    for (int it = 0; it < 2; ++it) {
      int seg = w * 2 + it;
      int ar = bm + seg * 16 + srow;
      int br = bn + seg * 16 + srow;
      gload_lds16(A  + (size_t)ar * K + kt + scol8, (char*)As + seg * 1024 + lane * 16);
      gload_lds16(Bt + (size_t)br * K + kt + scol8, (char*)Bs + seg * 1024 + lane * 16);
    }
    __syncthreads();
    bf16x8 af[4], bfr[4];
#pragma unroll
    for (int i = 0; i < 4; ++i) {
      int mrow = wr + i * 16 + (lane & 15);
      af[i] = *reinterpret_cast<const bf16x8*>((const char*)As + mrow * 64 + (lane >> 4) * 16);
    }
#pragma unroll
    for (int j = 0; j < 4; ++j) {
      int nrow = wc + j * 16 + (lane & 15);
      bfr[j] = *reinterpret_cast<const bf16x8*>((const char*)Bs + nrow * 64 + (lane >> 4) * 16);
    }
#pragma unroll
    for (int i = 0; i < 4; ++i)
#pragma unroll
      for (int j = 0; j < 4; ++j)
        acc[i][j] = __builtin_amdgcn_mfma_f32_16x16x32_bf16(af[i], bfr[j], acc[i][j], 0, 0, 0);
  }

#pragma unroll
  for (int i = 0; i < 4; ++i)
#pragma unroll
    for (int j = 0; j < 4; ++j)
#pragma unroll
      for (int r = 0; r < 4; ++r) {
        int mm = bm + wr + i * 16 + (lane >> 4) * 4 + r;
        int nn = bn + wc + j * 16 + (lane & 15);
        float val = acc[i][j][r];
        if (F32OUT)
          Cf[(size_t)mm * N + nn] = val + bias[nn];
        else
          Cb[(size_t)mm * N + nn] = (bf16_t)val;
      }
}

// ---------------- RoPE in-place on q,k of qkv (rows 1..N-1) ----------------
__global__ __launch_bounds__(256) void k_rope(bf16_t* __restrict__ qkv,
                                              const float* __restrict__ psin,
                                              const float* __restrict__ pcos) {
  const int i = blockIdx.x + 1;
  const int t = threadIdx.x;
#pragma unroll
  for (int itr = 0; itr < 4; ++itr) {
    int pidx = itr * 256 + t;          // 0..1023 pairs
    int half = pidx >> 9;              // 0=q, 1=k
    int pp   = pidx & 511;
    int hh = pp >> 5, tt = pp & 31;
    size_t off = (size_t)i * QKVN + half * 1024 + hh * 64 + tt * 2;
    float sn = psin[(size_t)(i - 1) * 32 + tt];
    float cs = pcos[(size_t)(i - 1) * 32 + tt];
    unsigned int u = *reinterpret_cast<const unsigned int*>(qkv + off);
    float x0 = bf2f(__builtin_bit_cast(bf16_t, (unsigned short)(u & 0xffffu)));
    float x1 = bf2f(__builtin_bit_cast(bf16_t, (unsigned short)(u >> 16)));
    unsigned short b0 = __builtin_bit_cast(unsigned short, (bf16_t)(x0 * cs - x1 * sn));
    unsigned short b1 = __builtin_bit_cast(unsigned short, (bf16_t)(x1 * cs + x0 * sn));
    *reinterpret_cast<unsigned int*>(qkv + off) = (unsigned int)b0 | ((unsigned int)b1 << 16);
  }
}

// ---------------- V transpose per head: qkv v-part -> Vt[h][d][n] ----------------
__global__ __launch_bounds__(256) void k_vtrans(const bf16_t* __restrict__ qkv,
                                                bf16_t* __restrict__ Vt) {
  __shared__ bf16_t tile[64][72];
  const int n0 = blockIdx.x * 64;
  const int h  = blockIdx.y;
  const int r  = threadIdx.x >> 2;   // 0..63
  const int cq = threadIdx.x & 3;    // 0..3 (16-wide chunks)
  const bf16_t* src = qkv + (size_t)(n0 + r) * QKVN + 2048 + h * DH + cq * 16;
  bf16x8 v0 = *reinterpret_cast<const bf16x8*>(src);
  bf16x8 v1 = *reinterpret_cast<const bf16x8*>(src + 8);
#pragma unroll
  for (int e = 0; e < 8; ++e) { tile[r][cq * 16 + e] = v0[e]; tile[r][cq * 16 + 8 + e] = v1[e]; }
  __syncthreads();
  const int d = r;
  bf16x8 o0, o1;
#pragma unroll
  for (int e = 0; e < 8; ++e) { o0[e] = tile[cq * 16 + e][d]; o1[e] = tile[cq * 16 + 8 + e][d]; }
  bf16_t* dst = Vt + ((size_t)h * DH + d) * NTOK + n0 + cq * 16;
  *reinterpret_cast<bf16x8*>(dst)     = o0;
  *reinterpret_cast<bf16x8*>(dst + 8) = o1;
}

// ---------------- flash attention, wave-split-K + double-buffered staging ----------------
// grid: (NTOK/64, NH), 512 threads (8 waves).
// waves 0-3: q-rows (w&3)*16.., even k-tiles; waves 4-7: same q-rows, odd k-tiles.
// LDS: Ks[2 buf][2 tile][64][64], Vs same, Ps per wave, padc. 84 KB.
__global__ __launch_bounds__(512) void k_attn(const bf16_t* __restrict__ qkv,
                                              const bf16_t* __restrict__ Vt,
                                              const int* __restrict__ mask,
                                              bf16_t* __restrict__ Ob) {
  __shared__ alignas(16) bf16_t Ks[2][2][64][64];  // 32 KB
  __shared__ alignas(16) bf16_t Vs[2][2][64][64];  // 32 KB
  __shared__ alignas(16) bf16_t Ps[8][1024];       // 16 KB
  __shared__ unsigned char padc[NTOK];             //  2 KB

  const int h  = blockIdx.y;
  const int q0 = blockIdx.x * 64;
  const int tid = threadIdx.x, lane = tid & 63, w = tid >> 6;
  const int g = w >> 2;        // k-tile parity group
  const int wq = w & 3;        // q sub-tile

  for (int j = tid; j < NTOK; j += 512)
    padc[j] = (j == 0) ? 1 : (unsigned char)(mask[j - 1] != 0);

  // Q fragments (16 rows per wave), rope already applied
  const int qrow = q0 + wq * 16 + (lane & 15);
  bf16x8 qf[2];
  {
    const bf16_t* qp = qkv + (size_t)qrow * QKVN + h * DH + (lane >> 4) * 8;
    qf[0] = *reinterpret_cast<const bf16x8*>(qp);
    qf[1] = *reinterpret_cast<const bf16x8*>(qp + 32);
  }

  float m_run[4], l_run[4];
  f32x4 acc[4];
#pragma unroll
  for (int r = 0; r < 4; ++r) { m_run[r] = -1e30f; l_run[r] = 0.f; }
#pragma unroll
  for (int df = 0; df < 4; ++df) acc[df] = f32x4{0.f, 0.f, 0.f, 0.f};

  const float scale = 0.03125f;  // 1024^-0.5
  const int kmax = (q0 == 0) ? NTOK : (q0 + 64);
  const int nTiles = kmax >> 6;          // >= 2 always
  const int nIters = (nTiles + 1) >> 1;

  // staging geometry: 32 segs of 1KB (16 K-pair + 16 V-pair); wave w<4 -> K, w>=4 -> V
  const int r8 = lane >> 3;               // row within 8-row seg
  const int sw = (lane & 7) ^ r8;         // inverse-swizzled 16B col
  const int segb = wq * 4;

  // prologue: stage pair 0 into buf 0
#pragma unroll
  for (int i = 0; i < 4; ++i) {
    int s = segb + i;
    int tt = s >> 3, rb = (s & 7) * 8;
    if (w < 4)
      gload_lds16(qkv + (size_t)(tt * 64 + rb + r8) * QKVN + DIM + h * DH + sw * 8,
                  (char*)Ks + s * 1024 + lane * 16);
    else
      gload_lds16(Vt + ((size_t)h * DH + rb + r8) * NTOK + tt * 64 + sw * 8,
                  (char*)Vs + s * 1024 + lane * 16);
  }

  for (int it = 0; it < nIters; ++it) {
    const int buf = it & 1;
    if (it + 1 < nIters) {
      const int k0p = (it + 1) * 128;
#pragma unroll
      for (int i = 0; i < 4; ++i) {
        int s = segb + i;
        int tt = s >> 3, rb = (s & 7) * 8;
        if (w < 4)
          gload_lds16(qkv + (size_t)(k0p + tt * 64 + rb + r8) * QKVN + DIM + h * DH + sw * 8,
                      (char*)Ks + (buf ^ 1) * 16384 + s * 1024 + lane * 16);
        else
          gload_lds16(Vt + ((size_t)h * DH + rb + r8) * NTOK + k0p + tt * 64 + sw * 8,
                      (char*)Vs + (buf ^ 1) * 16384 + s * 1024 + lane * 16);
      }
      asm volatile("s_waitcnt vmcnt(4)" ::: "memory");
    } else {
      asm volatile("s_waitcnt vmcnt(0)" ::: "memory");
    }
    __builtin_amdgcn_s_barrier();

    const int tile = 2 * it + g;
    if (tile < nTiles) {
      const int k0 = tile * 64;
      const char* KsT = (const char*)Ks + buf * 16384 + g * 8192;
      const char* VsT = (const char*)Vs + buf * 16384 + g * 8192;

      // S = Q K^T  (16 rows x 64 keys per wave)
      f32x4 sfr[4];
      __builtin_amdgcn_s_setprio(1);
#pragma unroll
      for (int jf = 0; jf < 4; ++jf) {
        f32x4 s = f32x4{0.f, 0.f, 0.f, 0.f};
        int jl = jf * 16 + (lane & 15);
#pragma unroll
        for (int ks = 0; ks < 2; ++ks) {
          int inrow = (ks * 64 + (lane >> 4) * 16) ^ ((jl & 7) << 4);
          bf16x8 kf = *reinterpret_cast<const bf16x8*>(KsT + jl * 128 + inrow);
          s = __builtin_amdgcn_mfma_f32_16x16x32_bf16(qf[ks], kf, s, 0, 0, 0);
        }
        sfr[jf] = s;
      }
      __builtin_amdgcn_s_setprio(0);

      // mask + scale, row max
      float sv[4][4];
      float pmax[4] = {-1e30f, -1e30f, -1e30f, -1e30f};
#pragma unroll
      for (int jf = 0; jf < 4; ++jf) {
        int j = k0 + jf * 16 + (lane & 15);
        bool padj = padc[j] != 0;
#pragma unroll
        for (int r = 0; r < 4; ++r) {
          int i = q0 + wq * 16 + (lane >> 4) * 4 + r;
          bool ok = padj && ((j <= i) || (i == 0));
          sv[jf][r] = ok ? sfr[jf][r] * scale : -1e30f;
          pmax[r] = fmaxf(pmax[r], sv[jf][r]);
        }
      }
#pragma unroll
      for (int o = 1; o < 16; o <<= 1)
#pragma unroll
        for (int r = 0; r < 4; ++r) pmax[r] = fmaxf(pmax[r], __shfl_xor(pmax[r], o, 64));

      // online softmax update (pe explicitly zeroed for masked entries:
      // a wave group's first tiles can be fully masked -> m_run still -1e30)
      float corr[4];
#pragma unroll
      for (int r = 0; r < 4; ++r) {
        float mnew = fmaxf(m_run[r], pmax[r]);
        corr[r] = __expf(m_run[r] - mnew);
        m_run[r] = mnew;
      }
      float rsum[4] = {0.f, 0.f, 0.f, 0.f};
#pragma unroll
      for (int jf = 0; jf < 4; ++jf)
#pragma unroll
        for (int r = 0; r < 4; ++r) {
          float pe = (sv[jf][r] > -5e29f) ? __expf(sv[jf][r] - m_run[r]) : 0.f;
          rsum[r] += pe;
          int m = (lane >> 4) * 4 + r;
          int jloc = jf * 16 + (lane & 15);
          *reinterpret_cast<bf16_t*>((char*)&Ps[w][0] + m * 128 + ((jloc * 2) ^ ((m & 7) << 4))) =
              (bf16_t)pe;
        }
#pragma unroll
      for (int o = 1; o < 16; o <<= 1)
#pragma unroll
        for (int r = 0; r < 4; ++r) rsum[r] += __shfl_xor(rsum[r], o, 64);
#pragma unroll
      for (int r = 0; r < 4; ++r) l_run[r] = l_run[r] * corr[r] + rsum[r];
#pragma unroll
      for (int df = 0; df < 4; ++df)
#pragma unroll
        for (int r = 0; r < 4; ++r) acc[df][r] *= corr[r];

      // O += P V
      __builtin_amdgcn_s_setprio(1);
#pragma unroll
      for (int ks = 0; ks < 2; ++ks) {
        int mm = lane & 15;
        int inrow = (ks * 64 + (lane >> 4) * 16) ^ ((mm & 7) << 4);
        bf16x8 pa = *reinterpret_cast<const bf16x8*>((const char*)&Ps[w][0] + mm * 128 + inrow);
#pragma unroll
        for (int df = 0; df < 4; ++df) {
          int d = df * 16 + (lane & 15);
          int vin = (ks * 64 + (lane >> 4) * 16) ^ ((d & 7) << 4);
          bf16x8 vf = *reinterpret_cast<const bf16x8*>(VsT + d * 128 + vin);
          acc[df] = __builtin_amdgcn_mfma_f32_16x16x32_bf16(pa, vf, acc[df], 0, 0, 0);
        }
      }
      __builtin_amdgcn_s_setprio(0);
    }
    __builtin_amdgcn_s_barrier();
  }

  // merge the two k-parity groups' partial softmax states (reuse Ks as f32 scratch)
  float* comb = (float*)Ks;
  if (w >= 4) {
    float* p = comb + ((size_t)(w - 4) * 64 + lane) * 24;
#pragma unroll
    for (int df = 0; df < 4; ++df)
#pragma unroll
      for (int r = 0; r < 4; ++r) p[df * 4 + r] = acc[df][r];
#pragma unroll
    for (int r = 0; r < 4; ++r) { p[16 + r] = m_run[r]; p[20 + r] = l_run[r]; }
  }
  __syncthreads();
  if (w < 4) {
    const float* p = comb + ((size_t)w * 64 + lane) * 24;
    float a1[4], a2[4], lM[4];
#pragma unroll
    for (int r = 0; r < 4; ++r) {
      float m2 = p[16 + r], l2 = p[20 + r];
      float mn = fmaxf(m_run[r], m2);
      a1[r] = __expf(m_run[r] - mn);
      a2[r] = __expf(m2 - mn);
      lM[r] = l_run[r] * a1[r] + l2 * a2[r];
    }
#pragma unroll
    for (int df = 0; df < 4; ++df)
#pragma unroll
      for (int r = 0; r < 4; ++r) {
        float v = acc[df][r] * a1[r] + p[df * 4 + r] * a2[r];
        int i = q0 + w * 16 + (lane >> 4) * 4 + r;
        Ob[(size_t)i * DIM + h * DH + df * 16 + (lane & 15)] = (bf16_t)(v / lM[r]);
      }
  }
}

// ---------------- host ----------------
extern "C" void kernel_launch(void* const* d_in, const int* in_sizes, int n_in,
                              void* d_out, int out_size, void* d_ws, size_t ws_size,
                              hipStream_t stream) {
  const float* x       = (const float*)d_in[0];
  const float* pos_sin = (const float*)d_in[1];
  const float* pos_cos = (const float*)d_in[2];
  const int*   mask    = (const int*)d_in[3];
  const float* ln_s    = (const float*)d_in[4];
  const float* ln_b    = (const float*)d_in[5];
  const float* w_qkv   = (const float*)d_in[6];
  const float* w_out   = (const float*)d_in[7];
  const float* b_out   = (const float*)d_in[8];
  float* out = (float*)d_out;

  if (ws_size < 33554432u) return;

  char* ws = (char*)d_ws;
  bf16_t* xn  = (bf16_t*)(ws + 0);          //  4 MiB: 2048x1024
  bf16_t* qkv = (bf16_t*)(ws + 4194304);    // 12 MiB: 2048x3072
  bf16_t* Wqt = (bf16_t*)(ws + 16777216);   //  6 MiB: 3072x1024
  bf16_t* Wot = (bf16_t*)(ws + 23068672);   //  2 MiB: 1024x1024
  bf16_t* Vt  = (bf16_t*)(ws + 25165824);   //  4 MiB: 16x64x2048
  bf16_t* Ob  = (bf16_t*)(ws + 29360128);   //  4 MiB: 2048x1024

  k_ln<<<NTOK, 256, 0, stream>>>(x, ln_s, ln_b, xn);
  k_tc<<<dim3(48, 16), 256, 0, stream>>>(w_qkv, Wqt, 1024, 3072);
  k_tc<<<dim3(16, 16), 256, 0, stream>>>(w_out, Wot, 1024, 1024);
  k_gemm_bt<0><<<dim3(16, 24), 256, 0, stream>>>(xn, Wqt, qkv, nullptr, nullptr,
                                                 NTOK, QKVN, DIM);
  k_rope<<<NTOK - 1, 256, 0, stream>>>(qkv, pos_sin, pos_cos);
  k_vtrans<<<dim3(32, 16), 256, 0, stream>>>(qkv, Vt);
  k_attn<<<dim3(32, 16), 512, 0, stream>>>(qkv, Vt, mask, Ob);
  k_gemm_bt<1><<<dim3(16, 8), 256, 0, stream>>>(Ob, Wot, nullptr, out, b_out,
                                                NTOK, DIM, DIM);
}

// Round 3
// 146.767 us; speedup vs baseline: 1.0913x; 1.0913x over previous
//
#include <hip/hip_runtime.h>
#include <hip/hip_bf16.h>
#include <stdint.h>

typedef __bf16 bf16_t;
typedef __bf16 bf16x8 __attribute__((ext_vector_type(8)));
typedef __bf16 bf16x4 __attribute__((ext_vector_type(4)));
typedef float  f32x4  __attribute__((ext_vector_type(4)));

#define DEV __device__ __forceinline__

static constexpr int NTOK = 2048;
static constexpr int DIM  = 1024;
static constexpr int NH   = 16;
static constexpr int DH   = 64;
static constexpr int QKVN = 3072;
static constexpr int SLOTS_PER_HEAD = 80;   // sum over qi of ceil((qi+1)/8)
static constexpr int PART_STRIDE = 8704;    // 64x64 bf16 (8192) + m[64] f32 + l[64] f32

DEV void gload_lds16(const void* g, void* l) {
  __builtin_amdgcn_global_load_lds(
      (__attribute__((address_space(1))) void*)(g),
      (__attribute__((address_space(3))) void*)(l), 16, 0, 0);
}

DEV float bf2f(bf16_t b) { return (float)b; }

// ---------------- LayerNorm + cast to bf16 ----------------
__global__ __launch_bounds__(256) void k_ln(const float* __restrict__ x,
                                            const float* __restrict__ gamma,
                                            const float* __restrict__ beta,
                                            bf16_t* __restrict__ xn) {
  const int row = blockIdx.x;
  const int t = threadIdx.x;
  const float4* x4 = reinterpret_cast<const float4*>(x);
  float4 v = x4[(size_t)row * 256 + t];
  float s  = v.x + v.y + v.z + v.w;
  float s2 = v.x * v.x + v.y * v.y + v.z * v.z + v.w * v.w;
#pragma unroll
  for (int o = 1; o < 64; o <<= 1) {
    s  += __shfl_xor(s, o, 64);
    s2 += __shfl_xor(s2, o, 64);
  }
  __shared__ float red[8];
  const int w = t >> 6, lane = t & 63;
  if (lane == 0) { red[w] = s; red[4 + w] = s2; }
  __syncthreads();
  s  = red[0] + red[1] + red[2] + red[3];
  s2 = red[4] + red[5] + red[6] + red[7];
  const float mu  = s * (1.0f / 1024.0f);
  const float var = s2 * (1.0f / 1024.0f) - mu * mu;
  const float inv = rsqrtf(var + 1e-6f);
  const float4 g = reinterpret_cast<const float4*>(gamma)[t];
  const float4 b = reinterpret_cast<const float4*>(beta)[t];
  bf16x4 o;
  o[0] = (bf16_t)((v.x - mu) * inv * g.x + b.x);
  o[1] = (bf16_t)((v.y - mu) * inv * g.y + b.y);
  o[2] = (bf16_t)((v.z - mu) * inv * g.z + b.z);
  o[3] = (bf16_t)((v.w - mu) * inv * g.w + b.w);
  *reinterpret_cast<bf16x4*>(xn + (size_t)row * DIM + t * 4) = o;
}

// ---------------- transpose + cast fp32 MxN -> bf16 NxM ----------------
__global__ __launch_bounds__(256) void k_tc(const float* __restrict__ src,
                                            bf16_t* __restrict__ dst,
                                            int M, int N) {
  __shared__ float tile[64][65];
  const int c0 = blockIdx.x * 64;
  const int r0 = blockIdx.y * 64;
  const int tx = threadIdx.x & 63;
  const int ty = threadIdx.x >> 6;
#pragma unroll
  for (int i = 0; i < 16; ++i) {
    int r = ty + i * 4;
    tile[r][tx] = src[(size_t)(r0 + r) * N + c0 + tx];
  }
  __syncthreads();
#pragma unroll
  for (int i = 0; i < 16; ++i) {
    int r = ty + i * 4;
    dst[(size_t)(c0 + r) * M + r0 + tx] = (bf16_t)tile[tx][r];
  }
}

// ---------------- GEMM: C[M,N] = A[M,K] * Bt[N,K]^T (+bias), BM=64 BN=128 ----------------
template <int F32OUT>
__global__ __launch_bounds__(256) void k_gemm64(const bf16_t* __restrict__ A,
                                                const bf16_t* __restrict__ Bt,
                                                bf16_t* __restrict__ Cb,
                                                float* __restrict__ Cf,
                                                const float* __restrict__ bias,
                                                int M, int N, int K) {
  __shared__ alignas(16) bf16_t As[64 * 32];    // 4 segs of 1KB
  __shared__ alignas(16) bf16_t Bs[128 * 32];   // 8 segs of 1KB
  const int tid = threadIdx.x, lane = tid & 63, w = tid >> 6;
  const int bm = blockIdx.x * 64, bn = blockIdx.y * 128;
  const int wr = (w >> 1) * 32, wc = (w & 1) * 64;
  f32x4 acc[2][4];
#pragma unroll
  for (int i = 0; i < 2; ++i)
#pragma unroll
    for (int j = 0; j < 4; ++j) acc[i][j] = f32x4{0.f, 0.f, 0.f, 0.f};

  const int srow  = lane >> 2;        // 0..15
  const int scol8 = (lane & 3) * 8;   // element offset in K

  for (int kt = 0; kt < K; kt += 32) {
    __syncthreads();
#pragma unroll
    for (int it = 0; it < 3; ++it) {
      int s = w * 3 + it;             // 12 segs: 0..3 = A, 4..11 = B
      if (s < 4)
        gload_lds16(A + (size_t)(bm + s * 16 + srow) * K + kt + scol8,
                    (char*)As + s * 1024 + lane * 16);
      else
        gload_lds16(Bt + (size_t)(bn + (s - 4) * 16 + srow) * K + kt + scol8,
                    (char*)Bs + (s - 4) * 1024 + lane * 16);
    }
    __syncthreads();
    bf16x8 af[2], bfr[4];
#pragma unroll
    for (int i = 0; i < 2; ++i) {
      int mrow = wr + i * 16 + (lane & 15);
      af[i] = *reinterpret_cast<const bf16x8*>((const char*)As + mrow * 64 + (lane >> 4) * 16);
    }
#pragma unroll
    for (int j = 0; j < 4; ++j) {
      int nrow = wc + j * 16 + (lane & 15);
      bfr[j] = *reinterpret_cast<const bf16x8*>((const char*)Bs + nrow * 64 + (lane >> 4) * 16);
    }
#pragma unroll
    for (int i = 0; i < 2; ++i)
#pragma unroll
      for (int j = 0; j < 4; ++j)
        acc[i][j] = __builtin_amdgcn_mfma_f32_16x16x32_bf16(af[i], bfr[j], acc[i][j], 0, 0, 0);
  }

#pragma unroll
  for (int i = 0; i < 2; ++i)
#pragma unroll
    for (int j = 0; j < 4; ++j)
#pragma unroll
      for (int r = 0; r < 4; ++r) {
        int mm = bm + wr + i * 16 + (lane >> 4) * 4 + r;
        int nn = bn + wc + j * 16 + (lane & 15);
        float val = acc[i][j][r];
        if (F32OUT)
          Cf[(size_t)mm * N + nn] = val + bias[nn];
        else
          Cb[(size_t)mm * N + nn] = (bf16_t)val;
      }
}

// ---------------- RoPE in-place on q,k of qkv (rows 1..N-1) ----------------
__global__ __launch_bounds__(256) void k_rope(bf16_t* __restrict__ qkv,
                                              const float* __restrict__ psin,
                                              const float* __restrict__ pcos) {
  const int i = blockIdx.x + 1;
  const int t = threadIdx.x;
#pragma unroll
  for (int itr = 0; itr < 4; ++itr) {
    int pidx = itr * 256 + t;          // 0..1023 pairs
    int half = pidx >> 9;              // 0=q, 1=k
    int pp   = pidx & 511;
    int hh = pp >> 5, tt = pp & 31;
    size_t off = (size_t)i * QKVN + half * 1024 + hh * 64 + tt * 2;
    float sn = psin[(size_t)(i - 1) * 32 + tt];
    float cs = pcos[(size_t)(i - 1) * 32 + tt];
    unsigned int u = *reinterpret_cast<const unsigned int*>(qkv + off);
    float x0 = bf2f(__builtin_bit_cast(bf16_t, (unsigned short)(u & 0xffffu)));
    float x1 = bf2f(__builtin_bit_cast(bf16_t, (unsigned short)(u >> 16)));
    unsigned short b0 = __builtin_bit_cast(unsigned short, (bf16_t)(x0 * cs - x1 * sn));
    unsigned short b1 = __builtin_bit_cast(unsigned short, (bf16_t)(x1 * cs + x0 * sn));
    *reinterpret_cast<unsigned int*>(qkv + off) = (unsigned int)b0 | ((unsigned int)b1 << 16);
  }
}

// ---------------- V transpose per head: qkv v-part -> Vt[h][d][n] ----------------
__global__ __launch_bounds__(256) void k_vtrans(const bf16_t* __restrict__ qkv,
                                                bf16_t* __restrict__ Vt) {
  __shared__ bf16_t tile[64][72];
  const int n0 = blockIdx.x * 64;
  const int h  = blockIdx.y;
  const int r  = threadIdx.x >> 2;   // 0..63
  const int cq = threadIdx.x & 3;    // 0..3 (16-wide chunks)
  const bf16_t* src = qkv + (size_t)(n0 + r) * QKVN + 2048 + h * DH + cq * 16;
  bf16x8 v0 = *reinterpret_cast<const bf16x8*>(src);
  bf16x8 v1 = *reinterpret_cast<const bf16x8*>(src + 8);
#pragma unroll
  for (int e = 0; e < 8; ++e) { tile[r][cq * 16 + e] = v0[e]; tile[r][cq * 16 + 8 + e] = v1[e]; }
  __syncthreads();
  const int d = r;
  bf16x8 o0, o1;
#pragma unroll
  for (int e = 0; e < 8; ++e) { o0[e] = tile[cq * 16 + e][d]; o1[e] = tile[cq * 16 + 8 + e][d]; }
  bf16_t* dst = Vt + ((size_t)h * DH + d) * NTOK + n0 + cq * 16;
  *reinterpret_cast<bf16x8*>(dst)     = o0;
  *reinterpret_cast<bf16x8*>(dst + 8) = o1;
}

// ---------------- flash attention partials ----------------
// grid: (80, 16). slot -> (qi, chunk). Each block: 64 q-rows x <=512 keys (causal only),
// 4 waves (16 q-rows each), k-tiles of 64 double-buffered. Unnormalized partial out.
__global__ __launch_bounds__(256) void k_attn_part(const bf16_t* __restrict__ qkv,
                                                   const bf16_t* __restrict__ Vt,
                                                   const int* __restrict__ mask,
                                                   char* __restrict__ part) {
  __shared__ alignas(16) bf16_t Ks[2][64][64];   // 16 KB
  __shared__ alignas(16) bf16_t Vs[2][64][64];   // 16 KB
  __shared__ alignas(16) bf16_t Ps[4][1024];     //  8 KB
  __shared__ unsigned char padc[512];

  const int h = blockIdx.y;
  const int slot = blockIdx.x;
  // decode slot -> (qi, c):  nch(qi) = (qi>>3)+1, cum(qi) = 4g(g+1) + (qi&7)(g+1)
  int g;
  if (slot < 8) g = 0; else if (slot < 24) g = 1; else if (slot < 48) g = 2; else g = 3;
  const unsigned tt = slot - 4 * g * (g + 1);
  const unsigned qi = (g << 3) + tt / (g + 1);
  const unsigned c  = tt - (tt / (g + 1)) * (g + 1);
  const int q0 = qi * 64;
  const int kbeg = c * 512;
  const int kvlen = (qi + 1) * 64;
  const int klen = min(512, kvlen - kbeg);
  const int ntiles = klen >> 6;

  const int tid = threadIdx.x, lane = tid & 63, w = tid >> 6;

  for (int jr = tid; jr < klen; jr += 256) {
    int j = kbeg + jr;
    padc[jr] = (j == 0) ? 1 : (unsigned char)(mask[j - 1] != 0);
  }

  const int qrow = q0 + w * 16 + (lane & 15);
  bf16x8 qf[2];
  {
    const bf16_t* qp = qkv + (size_t)qrow * QKVN + h * DH + (lane >> 4) * 8;
    qf[0] = *reinterpret_cast<const bf16x8*>(qp);
    qf[1] = *reinterpret_cast<const bf16x8*>(qp + 32);
  }

  float m_run[4], l_run[4];
  f32x4 acc[4];
#pragma unroll
  for (int r = 0; r < 4; ++r) { m_run[r] = -1e30f; l_run[r] = 0.f; }
#pragma unroll
  for (int df = 0; df < 4; ++df) acc[df] = f32x4{0.f, 0.f, 0.f, 0.f};

  const float scale = 0.03125f;
  const int r8 = lane >> 3;           // 0..7
  const int sw = (lane & 7) ^ r8;     // inverse-swizzled 16B unit

  // prologue: stage tile 0 into buf 0  (wave w: K segs 2w,2w+1 and V segs 2w,2w+1)
#pragma unroll
  for (int i = 0; i < 2; ++i) {
    int seg = w * 2 + i;
    int row = seg * 8 + r8;
    gload_lds16(qkv + (size_t)(kbeg + row) * QKVN + DIM + h * DH + sw * 8,
                (char*)Ks + seg * 1024 + lane * 16);
    gload_lds16(Vt + ((size_t)h * DH + row) * NTOK + kbeg + sw * 8,
                (char*)Vs + seg * 1024 + lane * 16);
  }

  for (int it = 0; it < ntiles; ++it) {
    const int buf = it & 1;
    if (it + 1 < ntiles) {
      const int kb = kbeg + (it + 1) * 64;
#pragma unroll
      for (int i = 0; i < 2; ++i) {
        int seg = w * 2 + i;
        int row = seg * 8 + r8;
        gload_lds16(qkv + (size_t)(kb + row) * QKVN + DIM + h * DH + sw * 8,
                    (char*)Ks + (buf ^ 1) * 8192 + seg * 1024 + lane * 16);
        gload_lds16(Vt + ((size_t)h * DH + row) * NTOK + kb + sw * 8,
                    (char*)Vs + (buf ^ 1) * 8192 + seg * 1024 + lane * 16);
      }
      asm volatile("s_waitcnt vmcnt(4)" ::: "memory");
    } else {
      asm volatile("s_waitcnt vmcnt(0)" ::: "memory");
    }
    __builtin_amdgcn_s_barrier();

    const int k0 = kbeg + it * 64;
    const char* KsT = (const char*)Ks + buf * 8192;
    const char* VsT = (const char*)Vs + buf * 8192;

    // S = Q K^T
    f32x4 sfr[4];
    __builtin_amdgcn_s_setprio(1);
#pragma unroll
    for (int jf = 0; jf < 4; ++jf) {
      f32x4 s = f32x4{0.f, 0.f, 0.f, 0.f};
      int jl = jf * 16 + (lane & 15);
#pragma unroll
      for (int ks = 0; ks < 2; ++ks) {
        int inrow = (ks * 64 + (lane >> 4) * 16) ^ ((jl & 7) << 4);
        bf16x8 kf = *reinterpret_cast<const bf16x8*>(KsT + jl * 128 + inrow);
        s = __builtin_amdgcn_mfma_f32_16x16x32_bf16(qf[ks], kf, s, 0, 0, 0);
      }
      sfr[jf] = s;
    }
    __builtin_amdgcn_s_setprio(0);

    // mask + scale, row max
    float sv[4][4];
    float pmax[4] = {-1e30f, -1e30f, -1e30f, -1e30f};
#pragma unroll
    for (int jf = 0; jf < 4; ++jf) {
      int jl = jf * 16 + (lane & 15);
      int j = k0 + jl;
      bool padj = padc[j - kbeg] != 0;
#pragma unroll
      for (int r = 0; r < 4; ++r) {
        int i = q0 + w * 16 + (lane >> 4) * 4 + r;
        bool ok = padj && (j <= i);
        sv[jf][r] = ok ? sfr[jf][r] * scale : -1e30f;
        pmax[r] = fmaxf(pmax[r], sv[jf][r]);
      }
    }
#pragma unroll
    for (int o = 1; o < 16; o <<= 1)
#pragma unroll
      for (int r = 0; r < 4; ++r) pmax[r] = fmaxf(pmax[r], __shfl_xor(pmax[r], o, 64));

    float corr[4];
#pragma unroll
    for (int r = 0; r < 4; ++r) {
      float mnew = fmaxf(m_run[r], pmax[r]);
      corr[r] = __expf(m_run[r] - mnew);
      m_run[r] = mnew;
    }
    float rsum[4] = {0.f, 0.f, 0.f, 0.f};
#pragma unroll
    for (int jf = 0; jf < 4; ++jf)
#pragma unroll
      for (int r = 0; r < 4; ++r) {
        float pe = (sv[jf][r] > -5e29f) ? __expf(sv[jf][r] - m_run[r]) : 0.f;
        rsum[r] += pe;
        int m = (lane >> 4) * 4 + r;
        int jloc = jf * 16 + (lane & 15);
        *reinterpret_cast<bf16_t*>((char*)&Ps[w][0] + m * 128 + ((jloc * 2) ^ ((m & 7) << 4))) =
            (bf16_t)pe;
      }
#pragma unroll
    for (int o = 1; o < 16; o <<= 1)
#pragma unroll
      for (int r = 0; r < 4; ++r) rsum[r] += __shfl_xor(rsum[r], o, 64);
#pragma unroll
    for (int r = 0; r < 4; ++r) l_run[r] = l_run[r] * corr[r] + rsum[r];
#pragma unroll
    for (int df = 0; df < 4; ++df)
#pragma unroll
      for (int r = 0; r < 4; ++r) acc[df][r] *= corr[r];

    // O += P V
    __builtin_amdgcn_s_setprio(1);
#pragma unroll
    for (int ks = 0; ks < 2; ++ks) {
      int mm = lane & 15;
      int inrow = (ks * 64 + (lane >> 4) * 16) ^ ((mm & 7) << 4);
      bf16x8 pa = *reinterpret_cast<const bf16x8*>((const char*)&Ps[w][0] + mm * 128 + inrow);
#pragma unroll
      for (int df = 0; df < 4; ++df) {
        int d = df * 16 + (lane & 15);
        int vin = (ks * 64 + (lane >> 4) * 16) ^ ((d & 7) << 4);
        bf16x8 vf = *reinterpret_cast<const bf16x8*>(VsT + d * 128 + vin);
        acc[df] = __builtin_amdgcn_mfma_f32_16x16x32_bf16(pa, vf, acc[df], 0, 0, 0);
      }
    }
    __builtin_amdgcn_s_setprio(0);
    __builtin_amdgcn_s_barrier();
  }

  // write unnormalized partial
  char* pb = part + (size_t)(h * SLOTS_PER_HEAD + slot) * PART_STRIDE;
  bf16_t* po = (bf16_t*)pb;
  float* pm = (float*)(pb + 8192);
  float* pl = (float*)(pb + 8448);
#pragma unroll
  for (int df = 0; df < 4; ++df)
#pragma unroll
    for (int r = 0; r < 4; ++r) {
      int row = w * 16 + (lane >> 4) * 4 + r;
      po[row * 64 + df * 16 + (lane & 15)] = (bf16_t)acc[df][r];
    }
  if ((lane & 15) == 0) {
#pragma unroll
    for (int r = 0; r < 4; ++r) {
      int row = w * 16 + (lane >> 4) * 4 + r;
      pm[row] = m_run[r];
      pl[row] = l_run[r];
    }
  }
}

// ---------------- merge partials -> Ob ----------------
// grid (32, 16): block = (qi, head). 256 thr: thread owns (row = t>>2, 16 dims).
__global__ __launch_bounds__(256) void k_merge(const char* __restrict__ part,
                                               bf16_t* __restrict__ Ob) {
  const int qi = blockIdx.x, h = blockIdx.y;
  const int g = qi >> 3, nch = g + 1;
  const int cum = 4 * g * (g + 1) + (qi & 7) * nch;
  const int t = threadIdx.x;
  const int row = t >> 2, dq = t & 3;

  float acc[16];
#pragma unroll
  for (int e = 0; e < 16; ++e) acc[e] = 0.f;
  float M = -1e30f, L = 0.f;

  for (int c = 0; c < nch; ++c) {
    const char* pb = part + (size_t)(h * SLOTS_PER_HEAD + cum + c) * PART_STRIDE;
    float mc = ((const float*)(pb + 8192))[row];
    float lc = ((const float*)(pb + 8448))[row];
    bf16x8 o0 = *(const bf16x8*)(pb + row * 128 + dq * 32);
    bf16x8 o1 = *(const bf16x8*)(pb + row * 128 + dq * 32 + 16);
    float Mn = fmaxf(M, mc);
    float sOld = __expf(M - Mn), sNew = __expf(mc - Mn);
    M = Mn;
    L = L * sOld + lc * sNew;
#pragma unroll
    for (int e = 0; e < 8; ++e) acc[e]     = acc[e]     * sOld + (float)o0[e] * sNew;
#pragma unroll
    for (int e = 0; e < 8; ++e) acc[8 + e] = acc[8 + e] * sOld + (float)o1[e] * sNew;
  }
  const float inv = 1.0f / L;
  bf16x8 r0, r1;
#pragma unroll
  for (int e = 0; e < 8; ++e) { r0[e] = (bf16_t)(acc[e] * inv); r1[e] = (bf16_t)(acc[8 + e] * inv); }
  bf16_t* dst = Ob + (size_t)(qi * 64 + row) * DIM + h * DH + dq * 16;
  *reinterpret_cast<bf16x8*>(dst)     = r0;
  *reinterpret_cast<bf16x8*>(dst + 8) = r1;
}

// ---------------- row 0 (non-causal: attends all keys) ----------------
__global__ __launch_bounds__(256) void k_row0(const bf16_t* __restrict__ qkv,
                                              const bf16_t* __restrict__ Vt,
                                              const int* __restrict__ mask,
                                              bf16_t* __restrict__ Ob) {
  __shared__ float qv[64];
  __shared__ float sbuf[2048];
  __shared__ float red[4];
  __shared__ float red2[4][64];
  const int h = blockIdx.x, t = threadIdx.x, lane = t & 63, w = t >> 6;
  if (t < 64) qv[t] = (float)qkv[h * DH + t];   // row 0, un-roped (matches reference)
  __syncthreads();

  float sm[8];
  float lmax = -1e30f;
#pragma unroll
  for (int p = 0; p < 8; ++p) {
    int j = p * 256 + t;
    const bf16_t* kr = qkv + (size_t)j * QKVN + DIM + h * DH;
    float s = 0.f;
#pragma unroll
    for (int u = 0; u < 8; ++u) {
      bf16x8 kv8 = *reinterpret_cast<const bf16x8*>(kr + u * 8);
#pragma unroll
      for (int e = 0; e < 8; ++e) s += qv[u * 8 + e] * (float)kv8[e];
    }
    bool padj = (j == 0) || (mask[j - 1] != 0);
    s = padj ? s * 0.03125f : -1e30f;
    sm[p] = s;
    lmax = fmaxf(lmax, s);
  }
#pragma unroll
  for (int o = 1; o < 64; o <<= 1) lmax = fmaxf(lmax, __shfl_xor(lmax, o, 64));
  if (lane == 0) red[w] = lmax;
  __syncthreads();
  const float M = fmaxf(fmaxf(red[0], red[1]), fmaxf(red[2], red[3]));
  float ls = 0.f;
#pragma unroll
  for (int p = 0; p < 8; ++p) {
    float pe = __expf(sm[p] - M);
    sbuf[p * 256 + t] = pe;
    ls += pe;
  }
#pragma unroll
  for (int o = 1; o < 64; o <<= 1) ls += __shfl_xor(ls, o, 64);
  __syncthreads();
  if (lane == 0) red[w] = ls;
  __syncthreads();
  const float L = red[0] + red[1] + red[2] + red[3];

  const int d = t & 63, qr = t >> 6;
  const bf16_t* vr = Vt + ((size_t)h * DH + d) * NTOK + qr * 512;
  float a = 0.f;
#pragma unroll 8
  for (int u = 0; u < 64; ++u) {
    bf16x8 v8 = *reinterpret_cast<const bf16x8*>(vr + u * 8);
#pragma unroll
    for (int e = 0; e < 8; ++e) a += sbuf[qr * 512 + u * 8 + e] * (float)v8[e];
  }
  red2[qr][d] = a;
  __syncthreads();
  if (t < 64) {
    float o = (red2[0][t] + red2[1][t] + red2[2][t] + red2[3][t]) / L;
    Ob[h * DH + t] = (bf16_t)o;   // row 0
  }
}

// ---------------- host ----------------
extern "C" void kernel_launch(void* const* d_in, const int* in_sizes, int n_in,
                              void* d_out, int out_size, void* d_ws, size_t ws_size,
                              hipStream_t stream) {
  const float* x       = (const float*)d_in[0];
  const float* pos_sin = (const float*)d_in[1];
  const float* pos_cos = (const float*)d_in[2];
  const int*   mask    = (const int*)d_in[3];
  const float* ln_s    = (const float*)d_in[4];
  const float* ln_b    = (const float*)d_in[5];
  const float* w_qkv   = (const float*)d_in[6];
  const float* w_out   = (const float*)d_in[7];
  const float* b_out   = (const float*)d_in[8];
  float* out = (float*)d_out;

  if (ws_size < 33554432u) return;

  char* ws = (char*)d_ws;
  bf16_t* qkv  = (bf16_t*)(ws + 0);           // 12 MiB: 2048x3072
  bf16_t* Vt   = (bf16_t*)(ws + 12582912);    //  4 MiB: 16x64x2048
  bf16_t* Ob   = (bf16_t*)(ws + 16777216);    //  4 MiB: 2048x1024
  char*   part = ws + 20971520;               // 10.63 MiB: 16x80x8704 (overlays xn/Wqt/Wot)
  bf16_t* Wot  = (bf16_t*)(ws + 20971520);    //  2 MiB: written after merge
  bf16_t* xn   = (bf16_t*)(ws + 23068672);    //  4 MiB: dead after qkv gemm
  bf16_t* Wqt  = (bf16_t*)(ws + 27262976);    //  5.06 MiB region: dead after qkv gemm (6 MiB spills past? no: 27262976+6291456=33554432 exactly)

  k_ln<<<NTOK, 256, 0, stream>>>(x, ln_s, ln_b, xn);
  k_tc<<<dim3(48, 16), 256, 0, stream>>>(w_qkv, Wqt, 1024, 3072);
  k_gemm64<0><<<dim3(32, 24), 256, 0, stream>>>(xn, Wqt, qkv, nullptr, nullptr,
                                                NTOK, QKVN, DIM);
  k_rope<<<NTOK - 1, 256, 0, stream>>>(qkv, pos_sin, pos_cos);
  k_vtrans<<<dim3(32, 16), 256, 0, stream>>>(qkv, Vt);
  k_attn_part<<<dim3(SLOTS_PER_HEAD, NH), 256, 0, stream>>>(qkv, Vt, mask, part);
  k_merge<<<dim3(32, 16), 256, 0, stream>>>(part, Ob);
  k_row0<<<NH, 256, 0, stream>>>(qkv, Vt, mask, Ob);
  k_tc<<<dim3(16, 16), 256, 0, stream>>>(w_out, Wot, 1024, 1024);
  k_gemm64<1><<<dim3(32, 8), 256, 0, stream>>>(Ob, Wot, nullptr, out, b_out,
                                               NTOK, DIM, DIM);
}

// Round 4
// 137.537 us; speedup vs baseline: 1.1646x; 1.0671x over previous
//
#include <hip/hip_runtime.h>
#include <hip/hip_bf16.h>
#include <stdint.h>

typedef __bf16 bf16_t;
typedef __bf16 bf16x8 __attribute__((ext_vector_type(8)));
typedef __bf16 bf16x4 __attribute__((ext_vector_type(4)));
typedef float  f32x4  __attribute__((ext_vector_type(4)));

#define DEV __device__ __forceinline__

static constexpr int NTOK = 2048;
static constexpr int DIM  = 1024;
static constexpr int NH   = 16;
static constexpr int DH   = 64;
static constexpr int QKVN = 3072;
static constexpr int SLOTS_PER_HEAD = 40;   // sum over Q=0..15 of ceil((Q+1)/4)
static constexpr int PART_STRIDE = 17408;   // 128x64 bf16 (16384) + m2[128] f32 + l[128] f32
static constexpr float L2E = 1.44269504f;

DEV void gload_lds16(const void* g, void* l) {
  __builtin_amdgcn_global_load_lds(
      (__attribute__((address_space(1))) void*)(g),
      (__attribute__((address_space(3))) void*)(l), 16, 0, 0);
}

DEV float bf2f(bf16_t b) { return (float)b; }

// ---------------- fused: LayerNorm (blocks 0..2047) + w_qkv transpose-cast (2048..2815) ----
__global__ __launch_bounds__(256) void k_ln_tc(const float* __restrict__ x,
                                               const float* __restrict__ gamma,
                                               const float* __restrict__ beta,
                                               bf16_t* __restrict__ xn,
                                               const float* __restrict__ wsrc,
                                               bf16_t* __restrict__ wdst) {
  __shared__ float tile[64][65];
  __shared__ float red[8];
  int b = blockIdx.x;
  if (b < NTOK) {
    const int row = b;
    const int t = threadIdx.x;
    const float4* x4 = reinterpret_cast<const float4*>(x);
    float4 v = x4[(size_t)row * 256 + t];
    float s  = v.x + v.y + v.z + v.w;
    float s2 = v.x * v.x + v.y * v.y + v.z * v.z + v.w * v.w;
#pragma unroll
    for (int o = 1; o < 64; o <<= 1) {
      s  += __shfl_xor(s, o, 64);
      s2 += __shfl_xor(s2, o, 64);
    }
    const int w = t >> 6, lane = t & 63;
    if (lane == 0) { red[w] = s; red[4 + w] = s2; }
    __syncthreads();
    s  = red[0] + red[1] + red[2] + red[3];
    s2 = red[4] + red[5] + red[6] + red[7];
    const float mu  = s * (1.0f / 1024.0f);
    const float var = s2 * (1.0f / 1024.0f) - mu * mu;
    const float inv = rsqrtf(var + 1e-6f);
    const float4 g = reinterpret_cast<const float4*>(gamma)[t];
    const float4 bb = reinterpret_cast<const float4*>(beta)[t];
    bf16x4 o;
    o[0] = (bf16_t)((v.x - mu) * inv * g.x + bb.x);
    o[1] = (bf16_t)((v.y - mu) * inv * g.y + bb.y);
    o[2] = (bf16_t)((v.z - mu) * inv * g.z + bb.z);
    o[3] = (bf16_t)((v.w - mu) * inv * g.w + bb.w);
    *reinterpret_cast<bf16x4*>(xn + (size_t)row * DIM + t * 4) = o;
  } else {
    b -= NTOK;
    const int c0 = (b % 48) * 64;          // N = 3072
    const int r0 = (b / 48) * 64;          // M = 1024
    const int tx = threadIdx.x & 63;
    const int ty = threadIdx.x >> 6;
#pragma unroll
    for (int i = 0; i < 16; ++i) {
      int r = ty + i * 4;
      tile[r][tx] = wsrc[(size_t)(r0 + r) * 3072 + c0 + tx];
    }
    __syncthreads();
#pragma unroll
    for (int i = 0; i < 16; ++i) {
      int r = ty + i * 4;
      wdst[(size_t)(c0 + r) * 1024 + r0 + tx] = (bf16_t)tile[tx][r];
    }
  }
}

// ---------------- transpose + cast fp32 MxN -> bf16 NxM ----------------
__global__ __launch_bounds__(256) void k_tc(const float* __restrict__ src,
                                            bf16_t* __restrict__ dst,
                                            int M, int N) {
  __shared__ float tile[64][65];
  const int c0 = blockIdx.x * 64;
  const int r0 = blockIdx.y * 64;
  const int tx = threadIdx.x & 63;
  const int ty = threadIdx.x >> 6;
#pragma unroll
  for (int i = 0; i < 16; ++i) {
    int r = ty + i * 4;
    tile[r][tx] = src[(size_t)(r0 + r) * N + c0 + tx];
  }
  __syncthreads();
#pragma unroll
  for (int i = 0; i < 16; ++i) {
    int r = ty + i * 4;
    dst[(size_t)(c0 + r) * M + r0 + tx] = (bf16_t)tile[tx][r];
  }
}

// ---------------- GEMM 128x128 (m97 structure): C[M,N] = A[M,K] * Bt[N,K]^T ----------------
template <int F32OUT>
__global__ __launch_bounds__(256) void k_gemm_bt(const bf16_t* __restrict__ A,
                                                 const bf16_t* __restrict__ Bt,
                                                 bf16_t* __restrict__ Cb,
                                                 float* __restrict__ Cf,
                                                 const float* __restrict__ bias,
                                                 int M, int N, int K) {
  __shared__ alignas(16) bf16_t As[128 * 32];
  __shared__ alignas(16) bf16_t Bs[128 * 32];
  const int tid = threadIdx.x, lane = tid & 63, w = tid >> 6;
  const int bm = blockIdx.x * 128, bn = blockIdx.y * 128;
  const int wr = (w >> 1) * 64, wc = (w & 1) * 64;
  f32x4 acc[4][4];
#pragma unroll
  for (int i = 0; i < 4; ++i)
#pragma unroll
    for (int j = 0; j < 4; ++j) acc[i][j] = f32x4{0.f, 0.f, 0.f, 0.f};

  const int srow  = lane >> 2;
  const int scol8 = (lane & 3) * 8;

  for (int kt = 0; kt < K; kt += 32) {
    __syncthreads();
#pragma unroll
    for (int it = 0; it < 2; ++it) {
      int seg = w * 2 + it;
      int ar = bm + seg * 16 + srow;
      int br = bn + seg * 16 + srow;
      gload_lds16(A  + (size_t)ar * K + kt + scol8, (char*)As + seg * 1024 + lane * 16);
      gload_lds16(Bt + (size_t)br * K + kt + scol8, (char*)Bs + seg * 1024 + lane * 16);
    }
    __syncthreads();
    bf16x8 af[4], bfr[4];
#pragma unroll
    for (int i = 0; i < 4; ++i) {
      int mrow = wr + i * 16 + (lane & 15);
      af[i] = *reinterpret_cast<const bf16x8*>((const char*)As + mrow * 64 + (lane >> 4) * 16);
    }
#pragma unroll
    for (int j = 0; j < 4; ++j) {
      int nrow = wc + j * 16 + (lane & 15);
      bfr[j] = *reinterpret_cast<const bf16x8*>((const char*)Bs + nrow * 64 + (lane >> 4) * 16);
    }
#pragma unroll
    for (int i = 0; i < 4; ++i)
#pragma unroll
      for (int j = 0; j < 4; ++j)
        acc[i][j] = __builtin_amdgcn_mfma_f32_16x16x32_bf16(af[i], bfr[j], acc[i][j], 0, 0, 0);
  }

#pragma unroll
  for (int i = 0; i < 4; ++i)
#pragma unroll
    for (int j = 0; j < 4; ++j)
#pragma unroll
      for (int r = 0; r < 4; ++r) {
        int mm = bm + wr + i * 16 + (lane >> 4) * 4 + r;
        int nn = bn + wc + j * 16 + (lane & 15);
        float val = acc[i][j][r];
        if (F32OUT)
          Cf[(size_t)mm * N + nn] = val + bias[nn];
        else
          Cb[(size_t)mm * N + nn] = (bf16_t)val;
      }
}

// ---------------- GEMM 64x128 ----------------
template <int F32OUT>
__global__ __launch_bounds__(256) void k_gemm64(const bf16_t* __restrict__ A,
                                                const bf16_t* __restrict__ Bt,
                                                bf16_t* __restrict__ Cb,
                                                float* __restrict__ Cf,
                                                const float* __restrict__ bias,
                                                int M, int N, int K) {
  __shared__ alignas(16) bf16_t As[64 * 32];
  __shared__ alignas(16) bf16_t Bs[128 * 32];
  const int tid = threadIdx.x, lane = tid & 63, w = tid >> 6;
  const int bm = blockIdx.x * 64, bn = blockIdx.y * 128;
  const int wr = (w >> 1) * 32, wc = (w & 1) * 64;
  f32x4 acc[2][4];
#pragma unroll
  for (int i = 0; i < 2; ++i)
#pragma unroll
    for (int j = 0; j < 4; ++j) acc[i][j] = f32x4{0.f, 0.f, 0.f, 0.f};

  const int srow  = lane >> 2;
  const int scol8 = (lane & 3) * 8;

  for (int kt = 0; kt < K; kt += 32) {
    __syncthreads();
#pragma unroll
    for (int it = 0; it < 3; ++it) {
      int s = w * 3 + it;
      if (s < 4)
        gload_lds16(A + (size_t)(bm + s * 16 + srow) * K + kt + scol8,
                    (char*)As + s * 1024 + lane * 16);
      else
        gload_lds16(Bt + (size_t)(bn + (s - 4) * 16 + srow) * K + kt + scol8,
                    (char*)Bs + (s - 4) * 1024 + lane * 16);
    }
    __syncthreads();
    bf16x8 af[2], bfr[4];
#pragma unroll
    for (int i = 0; i < 2; ++i) {
      int mrow = wr + i * 16 + (lane & 15);
      af[i] = *reinterpret_cast<const bf16x8*>((const char*)As + mrow * 64 + (lane >> 4) * 16);
    }
#pragma unroll
    for (int j = 0; j < 4; ++j) {
      int nrow = wc + j * 16 + (lane & 15);
      bfr[j] = *reinterpret_cast<const bf16x8*>((const char*)Bs + nrow * 64 + (lane >> 4) * 16);
    }
#pragma unroll
    for (int i = 0; i < 2; ++i)
#pragma unroll
      for (int j = 0; j < 4; ++j)
        acc[i][j] = __builtin_amdgcn_mfma_f32_16x16x32_bf16(af[i], bfr[j], acc[i][j], 0, 0, 0);
  }

#pragma unroll
  for (int i = 0; i < 2; ++i)
#pragma unroll
    for (int j = 0; j < 4; ++j)
#pragma unroll
      for (int r = 0; r < 4; ++r) {
        int mm = bm + wr + i * 16 + (lane >> 4) * 4 + r;
        int nn = bn + wc + j * 16 + (lane & 15);
        float val = acc[i][j][r];
        if (F32OUT)
          Cf[(size_t)mm * N + nn] = val + bias[nn];
        else
          Cb[(size_t)mm * N + nn] = (bf16_t)val;
      }
}

// ---------------- fused: RoPE (q scaled by 1/32) + V transpose ----------------
__global__ __launch_bounds__(256) void k_rope_vt(bf16_t* __restrict__ qkv,
                                                 const float* __restrict__ psin,
                                                 const float* __restrict__ pcos,
                                                 bf16_t* __restrict__ Vt) {
  __shared__ bf16_t tile[64][72];
  int b = blockIdx.x;
  if (b < NTOK - 1) {
    const int i = b + 1;
    const int t = threadIdx.x;
#pragma unroll
    for (int itr = 0; itr < 4; ++itr) {
      int pidx = itr * 256 + t;
      int half = pidx >> 9;              // 0=q, 1=k
      int pp   = pidx & 511;
      int hh = pp >> 5, tt2 = pp & 31;
      size_t off = (size_t)i * QKVN + half * 1024 + hh * 64 + tt2 * 2;
      float sn = psin[(size_t)(i - 1) * 32 + tt2];
      float cs = pcos[(size_t)(i - 1) * 32 + tt2];
      unsigned int u = *reinterpret_cast<const unsigned int*>(qkv + off);
      float x0 = bf2f(__builtin_bit_cast(bf16_t, (unsigned short)(u & 0xffffu)));
      float x1 = bf2f(__builtin_bit_cast(bf16_t, (unsigned short)(u >> 16)));
      const float mul = half ? 1.0f : 0.03125f;   // fold softmax scale into q (exact 2^-5)
      unsigned short b0 = __builtin_bit_cast(unsigned short, (bf16_t)((x0 * cs - x1 * sn) * mul));
      unsigned short b1 = __builtin_bit_cast(unsigned short, (bf16_t)((x1 * cs + x0 * sn) * mul));
      *reinterpret_cast<unsigned int*>(qkv + off) = (unsigned int)b0 | ((unsigned int)b1 << 16);
    }
  } else {
    b -= (NTOK - 1);
    const int n0 = (b & 31) * 64;
    const int h  = b >> 5;
    const int r  = threadIdx.x >> 2;
    const int cq = threadIdx.x & 3;
    const bf16_t* src = qkv + (size_t)(n0 + r) * QKVN + 2048 + h * DH + cq * 16;
    bf16x8 v0 = *reinterpret_cast<const bf16x8*>(src);
    bf16x8 v1 = *reinterpret_cast<const bf16x8*>(src + 8);
#pragma unroll
    for (int e = 0; e < 8; ++e) { tile[r][cq * 16 + e] = v0[e]; tile[r][cq * 16 + 8 + e] = v1[e]; }
    __syncthreads();
    const int d = r;
    bf16x8 o0, o1;
#pragma unroll
    for (int e = 0; e < 8; ++e) { o0[e] = tile[cq * 16 + e][d]; o1[e] = tile[cq * 16 + 8 + e][d]; }
    bf16_t* dst = Vt + ((size_t)h * DH + d) * NTOK + n0 + cq * 16;
    *reinterpret_cast<bf16x8*>(dst)     = o0;
    *reinterpret_cast<bf16x8*>(dst + 8) = o1;
  }
}

// ---------------- flash attention partials: 128 q-rows x <=512 keys, 8 waves ----------------
__global__ __launch_bounds__(512) void k_attn_part(const bf16_t* __restrict__ qkv,
                                                   const bf16_t* __restrict__ Vt,
                                                   const int* __restrict__ mask,
                                                   char* __restrict__ part) {
  __shared__ alignas(16) bf16_t Ks[2][64][64];   // 16 KB
  __shared__ alignas(16) bf16_t Vs[2][64][64];   // 16 KB
  __shared__ alignas(16) bf16_t Ps[8][1024];     // 16 KB
  __shared__ unsigned char padc[512];

  const int h = blockIdx.y;
  const int slot = (SLOTS_PER_HEAD - 1) - blockIdx.x;   // heavy slots first
  int g;
  if (slot < 4) g = 0; else if (slot < 12) g = 1; else if (slot < 24) g = 2; else g = 3;
  const int tt = slot - 2 * g * (g + 1);
  const int Q = (g << 2) + tt / (g + 1);
  const int c = tt - (tt / (g + 1)) * (g + 1);
  const int q0 = Q * 128;
  const int kbeg = c * 512;
  const int kvlen = (Q + 1) * 128;
  const int klen = min(512, kvlen - kbeg);
  const int ntiles = klen >> 6;                 // 2,4,6,8

  const int tid = threadIdx.x, lane = tid & 63, w = tid >> 6;

  for (int jr = tid; jr < klen; jr += 512) {
    int j = kbeg + jr;
    padc[jr] = (j == 0) ? 1 : (unsigned char)(mask[j - 1] != 0);
  }

  const int iw = q0 + w * 16;                   // wave's first q-row
  bf16x8 qf[2];
  {
    const bf16_t* qp = qkv + (size_t)(iw + (lane & 15)) * QKVN + h * DH + (lane >> 4) * 8;
    qf[0] = *reinterpret_cast<const bf16x8*>(qp);
    qf[1] = *reinterpret_cast<const bf16x8*>(qp + 32);
  }
  bf16x8 ones;
#pragma unroll
  for (int e = 0; e < 8; ++e) ones[e] = (bf16_t)1.0f;

  float m_run[4], m2[4];
  f32x4 acc[4], accl;
#pragma unroll
  for (int r = 0; r < 4; ++r) { m_run[r] = -1e30f; m2[r] = -1e30f; }
#pragma unroll
  for (int df = 0; df < 4; ++df) acc[df] = f32x4{0.f, 0.f, 0.f, 0.f};
  accl = f32x4{0.f, 0.f, 0.f, 0.f};

  const int r8 = lane >> 3;
  const int sw = (lane & 7) ^ r8;

  // staging: 16 segs (0..7 K-rows, 8..15 V-rows); wave w stages segs 2w, 2w+1
#define STAGE(KB, BUF)                                                                   \
  {                                                                                      \
    _Pragma("unroll") for (int i2 = 0; i2 < 2; ++i2) {                                   \
      int s = w * 2 + i2;                                                                \
      if (s < 8) {                                                                       \
        int row = s * 8 + r8;                                                            \
        gload_lds16(qkv + (size_t)((KB) + row) * QKVN + DIM + h * DH + sw * 8,           \
                    (char*)Ks + (BUF)*8192 + s * 1024 + lane * 16);                      \
      } else {                                                                           \
        int row = (s - 8) * 8 + r8;                                                      \
        gload_lds16(Vt + ((size_t)h * DH + row) * NTOK + (KB) + sw * 8,                  \
                    (char*)Vs + (BUF)*8192 + (s - 8) * 1024 + lane * 16);                \
      }                                                                                  \
    }                                                                                    \
  }

  STAGE(kbeg, 0)

  for (int it = 0; it < ntiles; ++it) {
    const int buf = it & 1;
    if (it + 1 < ntiles) {
      STAGE(kbeg + (it + 1) * 64, buf ^ 1)
      asm volatile("s_waitcnt vmcnt(2)" ::: "memory");
    } else {
      asm volatile("s_waitcnt vmcnt(0)" ::: "memory");
    }
    __builtin_amdgcn_s_barrier();

    const int k0 = kbeg + it * 64;
    if (k0 <= iw + 15) {   // live tile for this wave
      const char* KsT = (const char*)Ks + buf * 8192;
      const char* VsT = (const char*)Vs + buf * 8192;

      f32x4 sfr[4];
      __builtin_amdgcn_s_setprio(1);
#pragma unroll
      for (int jf = 0; jf < 4; ++jf) {
        f32x4 s = f32x4{0.f, 0.f, 0.f, 0.f};
        int jl = jf * 16 + (lane & 15);
#pragma unroll
        for (int ks = 0; ks < 2; ++ks) {
          int inrow = (ks * 64 + (lane >> 4) * 16) ^ ((jl & 7) << 4);
          bf16x8 kf = *reinterpret_cast<const bf16x8*>(KsT + jl * 128 + inrow);
          s = __builtin_amdgcn_mfma_f32_16x16x32_bf16(qf[ks], kf, s, 0, 0, 0);
        }
        sfr[jf] = s;
      }
      __builtin_amdgcn_s_setprio(0);

      // local max (raw scores; masked entries may inflate m harmlessly)
      float pmax[4] = {-3e38f, -3e38f, -3e38f, -3e38f};
#pragma unroll
      for (int jf = 0; jf < 4; ++jf)
#pragma unroll
        for (int r = 0; r < 4; ++r) pmax[r] = fmaxf(pmax[r], sfr[jf][r]);

      int dok = (pmax[0] <= m_run[0] + 8.f) && (pmax[1] <= m_run[1] + 8.f) &&
                (pmax[2] <= m_run[2] + 8.f) && (pmax[3] <= m_run[3] + 8.f);
      if (!__all(dok)) {
#pragma unroll
        for (int o = 1; o < 16; o <<= 1)
#pragma unroll
          for (int r = 0; r < 4; ++r) pmax[r] = fmaxf(pmax[r], __shfl_xor(pmax[r], o, 64));
#pragma unroll
        for (int r = 0; r < 4; ++r) {
          float mnew = fmaxf(m_run[r], pmax[r]);
          float corr = __builtin_amdgcn_exp2f((m_run[r] - mnew) * L2E);
          m_run[r] = mnew;
          m2[r] = mnew * L2E;
          accl[r] *= corr;
#pragma unroll
          for (int df = 0; df < 4; ++df) acc[df][r] *= corr;
        }
      }

      const bool needC = (k0 + 63 > iw);
#pragma unroll
      for (int jf = 0; jf < 4; ++jf) {
        int jl = jf * 16 + (lane & 15);
        int j = k0 + jl;
        bool padj = padc[j - kbeg] != 0;
#pragma unroll
        for (int r = 0; r < 4; ++r) {
          float pe = __builtin_amdgcn_exp2f(__builtin_fmaf(sfr[jf][r], L2E, -m2[r]));
          bool ok = padj;
          if (needC) ok = ok && (j <= iw + (lane >> 4) * 4 + r);
          pe = ok ? pe : 0.f;
          int m = (lane >> 4) * 4 + r;
          *reinterpret_cast<bf16_t*>((char*)&Ps[w][0] + m * 128 + ((jl * 2) ^ ((m & 7) << 4))) =
              (bf16_t)pe;
        }
      }

      // O += P V ; l += P 1 (ones-column)
      __builtin_amdgcn_s_setprio(1);
#pragma unroll
      for (int ks = 0; ks < 2; ++ks) {
        int mm = lane & 15;
        int inrow = (ks * 64 + (lane >> 4) * 16) ^ ((mm & 7) << 4);
        bf16x8 pa = *reinterpret_cast<const bf16x8*>((const char*)&Ps[w][0] + mm * 128 + inrow);
        accl = __builtin_amdgcn_mfma_f32_16x16x32_bf16(pa, ones, accl, 0, 0, 0);
#pragma unroll
        for (int df = 0; df < 4; ++df) {
          int d = df * 16 + (lane & 15);
          int vin = (ks * 64 + (lane >> 4) * 16) ^ ((d & 7) << 4);
          bf16x8 vf = *reinterpret_cast<const bf16x8*>(VsT + d * 128 + vin);
          acc[df] = __builtin_amdgcn_mfma_f32_16x16x32_bf16(pa, vf, acc[df], 0, 0, 0);
        }
      }
      __builtin_amdgcn_s_setprio(0);
    }
    __builtin_amdgcn_s_barrier();
  }
#undef STAGE

  char* pb = part + (size_t)(h * SLOTS_PER_HEAD + slot) * PART_STRIDE;
  bf16_t* po = (bf16_t*)pb;
  float* pm = (float*)(pb + 16384);
  float* pl = (float*)(pb + 16896);
#pragma unroll
  for (int df = 0; df < 4; ++df)
#pragma unroll
    for (int r = 0; r < 4; ++r) {
      int row = w * 16 + (lane >> 4) * 4 + r;
      po[row * 64 + df * 16 + (lane & 15)] = (bf16_t)acc[df][r];
    }
  if ((lane & 15) == 0) {
#pragma unroll
    for (int r = 0; r < 4; ++r) {
      int row = w * 16 + (lane >> 4) * 4 + r;
      pm[row] = m2[r];       // log2 units
      pl[row] = accl[r];
    }
  }
}

// ---------------- merge partials -> Ob ----------------
// grid (16, 16): block = (Q, head). thread owns (row = t>>1, 32 dims).
__global__ __launch_bounds__(256) void k_merge(const char* __restrict__ part,
                                               bf16_t* __restrict__ Ob) {
  const int Q = blockIdx.x, h = blockIdx.y;
  const int g = Q >> 2, nch = g + 1;
  const int cum = 2 * g * (g + 1) + (Q & 3) * nch;
  const int t = threadIdx.x;
  const int row = t >> 1, half = t & 1;

  float acc[32];
#pragma unroll
  for (int e = 0; e < 32; ++e) acc[e] = 0.f;
  float M = -3e38f, L = 0.f;

  for (int c = 0; c < nch; ++c) {
    const char* pb = part + (size_t)(h * SLOTS_PER_HEAD + cum + c) * PART_STRIDE;
    float mc = ((const float*)(pb + 16384))[row];
    float lc = ((const float*)(pb + 16896))[row];
    float Mn = fmaxf(M, mc);
    float sOld = __builtin_amdgcn_exp2f(M - Mn), sNew = __builtin_amdgcn_exp2f(mc - Mn);
    M = Mn;
    L = L * sOld + lc * sNew;
    const bf16_t* od = (const bf16_t*)pb + row * 64 + half * 32;
#pragma unroll
    for (int e4 = 0; e4 < 4; ++e4) {
      bf16x8 o8 = *reinterpret_cast<const bf16x8*>(od + e4 * 8);
#pragma unroll
      for (int e = 0; e < 8; ++e)
        acc[e4 * 8 + e] = acc[e4 * 8 + e] * sOld + (float)o8[e] * sNew;
    }
  }
  const float inv = 1.0f / L;
  bf16_t* dst = Ob + (size_t)(Q * 128 + row) * DIM + h * DH + half * 32;
#pragma unroll
  for (int e4 = 0; e4 < 4; ++e4) {
    bf16x8 r8o;
#pragma unroll
    for (int e = 0; e < 8; ++e) r8o[e] = (bf16_t)(acc[e4 * 8 + e] * inv);
    *reinterpret_cast<bf16x8*>(dst + e4 * 8) = r8o;
  }
}

// ---------------- row 0 (non-causal: attends all keys) ----------------
__global__ __launch_bounds__(256) void k_row0(const bf16_t* __restrict__ qkv,
                                              const bf16_t* __restrict__ Vt,
                                              const int* __restrict__ mask,
                                              bf16_t* __restrict__ Ob) {
  __shared__ float qv[64];
  __shared__ float sbuf[2048];
  __shared__ float red[4];
  __shared__ float red2[4][64];
  const int h = blockIdx.x, t = threadIdx.x, lane = t & 63, w = t >> 6;
  if (t < 64) qv[t] = (float)qkv[h * DH + t];   // row 0 q, un-roped & un-scaled
  __syncthreads();

  float sm[8];
  float lmax = -1e30f;
#pragma unroll
  for (int p = 0; p < 8; ++p) {
    int j = p * 256 + t;
    const bf16_t* kr = qkv + (size_t)j * QKVN + DIM + h * DH;
    float s = 0.f;
#pragma unroll
    for (int u = 0; u < 8; ++u) {
      bf16x8 kv8 = *reinterpret_cast<const bf16x8*>(kr + u * 8);
#pragma unroll
      for (int e = 0; e < 8; ++e) s += qv[u * 8 + e] * (float)kv8[e];
    }
    bool padj = (j == 0) || (mask[j - 1] != 0);
    s = padj ? s * 0.03125f : -1e30f;
    sm[p] = s;
    lmax = fmaxf(lmax, s);
  }
#pragma unroll
  for (int o = 1; o < 64; o <<= 1) lmax = fmaxf(lmax, __shfl_xor(lmax, o, 64));
  if (lane == 0) red[w] = lmax;
  __syncthreads();
  const float M = fmaxf(fmaxf(red[0], red[1]), fmaxf(red[2], red[3]));
  float ls = 0.f;
#pragma unroll
  for (int p = 0; p < 8; ++p) {
    float pe = __expf(sm[p] - M);
    sbuf[p * 256 + t] = pe;
    ls += pe;
  }
#pragma unroll
  for (int o = 1; o < 64; o <<= 1) ls += __shfl_xor(ls, o, 64);
  __syncthreads();
  if (lane == 0) red[w] = ls;
  __syncthreads();
  const float L = red[0] + red[1] + red[2] + red[3];

  const int d = t & 63, qr = t >> 6;
  const bf16_t* vr = Vt + ((size_t)h * DH + d) * NTOK + qr * 512;
  float a = 0.f;
#pragma unroll 8
  for (int u = 0; u < 64; ++u) {
    bf16x8 v8 = *reinterpret_cast<const bf16x8*>(vr + u * 8);
#pragma unroll
    for (int e = 0; e < 8; ++e) a += sbuf[qr * 512 + u * 8 + e] * (float)v8[e];
  }
  red2[qr][d] = a;
  __syncthreads();
  if (t < 64) {
    float o = (red2[0][t] + red2[1][t] + red2[2][t] + red2[3][t]) / L;
    Ob[h * DH + t] = (bf16_t)o;
  }
}

// ---------------- host ----------------
extern "C" void kernel_launch(void* const* d_in, const int* in_sizes, int n_in,
                              void* d_out, int out_size, void* d_ws, size_t ws_size,
                              hipStream_t stream) {
  const float* x       = (const float*)d_in[0];
  const float* pos_sin = (const float*)d_in[1];
  const float* pos_cos = (const float*)d_in[2];
  const int*   mask    = (const int*)d_in[3];
  const float* ln_s    = (const float*)d_in[4];
  const float* ln_b    = (const float*)d_in[5];
  const float* w_qkv   = (const float*)d_in[6];
  const float* w_out   = (const float*)d_in[7];
  const float* b_out   = (const float*)d_in[8];
  float* out = (float*)d_out;

  if (ws_size < 33554432u) return;

  char* ws = (char*)d_ws;
  bf16_t* qkv  = (bf16_t*)(ws + 0);           // 12 MiB
  bf16_t* Vt   = (bf16_t*)(ws + 12582912);    //  4 MiB
  bf16_t* Ob   = (bf16_t*)(ws + 16777216);    //  4 MiB
  char*   part = ws + 20971520;               // 10.63 MiB (16*40*17408)
  bf16_t* xn   = (bf16_t*)(ws + 20971520);    //  4 MiB, dead before part written
  bf16_t* Wqt  = (bf16_t*)(ws + 25165824);    //  6 MiB, dead before part written
  bf16_t* Wot  = (bf16_t*)(ws + 20971520);    //  2 MiB, written after merge (part dead)

  k_ln_tc<<<NTOK + 768, 256, 0, stream>>>(x, ln_s, ln_b, xn, w_qkv, Wqt);
  k_gemm_bt<0><<<dim3(16, 24), 256, 0, stream>>>(xn, Wqt, qkv, nullptr, nullptr,
                                                 NTOK, QKVN, DIM);
  k_rope_vt<<<(NTOK - 1) + 512, 256, 0, stream>>>(qkv, pos_sin, pos_cos, Vt);
  k_attn_part<<<dim3(SLOTS_PER_HEAD, NH), 512, 0, stream>>>(qkv, Vt, mask, part);
  k_merge<<<dim3(16, 16), 256, 0, stream>>>(part, Ob);
  k_tc<<<dim3(16, 16), 256, 0, stream>>>(w_out, Wot, 1024, 1024);
  k_row0<<<NH, 256, 0, stream>>>(qkv, Vt, mask, Ob);
  k_gemm64<1><<<dim3(32, 8), 256, 0, stream>>>(Ob, Wot, nullptr, out, b_out,
                                               NTOK, DIM, DIM);
}

// Round 5
// 137.476 us; speedup vs baseline: 1.1651x; 1.0004x over previous
//
#include <hip/hip_runtime.h>
#include <hip/hip_bf16.h>
#include <stdint.h>

typedef __bf16 bf16_t;
typedef __bf16 bf16x8 __attribute__((ext_vector_type(8)));
typedef __bf16 bf16x4 __attribute__((ext_vector_type(4)));
typedef float  f32x4  __attribute__((ext_vector_type(4)));

#define DEV __device__ __forceinline__

static constexpr int NTOK = 2048;
static constexpr int DIM  = 1024;
static constexpr int NH   = 16;
static constexpr int DH   = 64;
static constexpr int QKVN = 3072;
static constexpr int SLOTS_PER_HEAD = 40;   // sum over Q=0..15 of ceil((Q+1)/4)
static constexpr int PART_STRIDE = 17408;   // 128x64 bf16 (16384) + m2[128] f32 + l[128] f32
static constexpr float L2E = 1.44269504f;

DEV void gload_lds16(const void* g, void* l) {
  __builtin_amdgcn_global_load_lds(
      (__attribute__((address_space(1))) void*)(g),
      (__attribute__((address_space(3))) void*)(l), 16, 0, 0);
}

DEV float bf2f(bf16_t b) { return (float)b; }

// ---------------- fused: LayerNorm (blocks 0..2047) + w_qkv transpose-cast (2048..2815) ----
__global__ __launch_bounds__(256) void k_ln_tc(const float* __restrict__ x,
                                               const float* __restrict__ gamma,
                                               const float* __restrict__ beta,
                                               bf16_t* __restrict__ xn,
                                               const float* __restrict__ wsrc,
                                               bf16_t* __restrict__ wdst) {
  __shared__ float tile[64][65];
  __shared__ float red[8];
  int b = blockIdx.x;
  if (b < NTOK) {
    const int row = b;
    const int t = threadIdx.x;
    const float4* x4 = reinterpret_cast<const float4*>(x);
    float4 v = x4[(size_t)row * 256 + t];
    float s  = v.x + v.y + v.z + v.w;
    float s2 = v.x * v.x + v.y * v.y + v.z * v.z + v.w * v.w;
#pragma unroll
    for (int o = 1; o < 64; o <<= 1) {
      s  += __shfl_xor(s, o, 64);
      s2 += __shfl_xor(s2, o, 64);
    }
    const int w = t >> 6, lane = t & 63;
    if (lane == 0) { red[w] = s; red[4 + w] = s2; }
    __syncthreads();
    s  = red[0] + red[1] + red[2] + red[3];
    s2 = red[4] + red[5] + red[6] + red[7];
    const float mu  = s * (1.0f / 1024.0f);
    const float var = s2 * (1.0f / 1024.0f) - mu * mu;
    const float inv = rsqrtf(var + 1e-6f);
    const float4 g = reinterpret_cast<const float4*>(gamma)[t];
    const float4 bb = reinterpret_cast<const float4*>(beta)[t];
    bf16x4 o;
    o[0] = (bf16_t)((v.x - mu) * inv * g.x + bb.x);
    o[1] = (bf16_t)((v.y - mu) * inv * g.y + bb.y);
    o[2] = (bf16_t)((v.z - mu) * inv * g.z + bb.z);
    o[3] = (bf16_t)((v.w - mu) * inv * g.w + bb.w);
    *reinterpret_cast<bf16x4*>(xn + (size_t)row * DIM + t * 4) = o;
  } else {
    b -= NTOK;
    const int c0 = (b % 48) * 64;          // N = 3072
    const int r0 = (b / 48) * 64;          // M = 1024
    const int tx = threadIdx.x & 63;
    const int ty = threadIdx.x >> 6;
#pragma unroll
    for (int i = 0; i < 16; ++i) {
      int r = ty + i * 4;
      tile[r][tx] = wsrc[(size_t)(r0 + r) * 3072 + c0 + tx];
    }
    __syncthreads();
#pragma unroll
    for (int i = 0; i < 16; ++i) {
      int r = ty + i * 4;
      wdst[(size_t)(c0 + r) * 1024 + r0 + tx] = (bf16_t)tile[tx][r];
    }
  }
}

// ---------------- transpose + cast fp32 MxN -> bf16 NxM ----------------
__global__ __launch_bounds__(256) void k_tc(const float* __restrict__ src,
                                            bf16_t* __restrict__ dst,
                                            int M, int N) {
  __shared__ float tile[64][65];
  const int c0 = blockIdx.x * 64;
  const int r0 = blockIdx.y * 64;
  const int tx = threadIdx.x & 63;
  const int ty = threadIdx.x >> 6;
#pragma unroll
  for (int i = 0; i < 16; ++i) {
    int r = ty + i * 4;
    tile[r][tx] = src[(size_t)(r0 + r) * N + c0 + tx];
  }
  __syncthreads();
#pragma unroll
  for (int i = 0; i < 16; ++i) {
    int r = ty + i * 4;
    dst[(size_t)(c0 + r) * M + r0 + tx] = (bf16_t)tile[tx][r];
  }
}

// ---------------- GEMM 128x128 (m97 structure): C[M,N] = A[M,K] * Bt[N,K]^T ----------------
template <int F32OUT>
__global__ __launch_bounds__(256) void k_gemm_bt(const bf16_t* __restrict__ A,
                                                 const bf16_t* __restrict__ Bt,
                                                 bf16_t* __restrict__ Cb,
                                                 float* __restrict__ Cf,
                                                 const float* __restrict__ bias,
                                                 int M, int N, int K) {
  __shared__ alignas(16) bf16_t As[128 * 32];
  __shared__ alignas(16) bf16_t Bs[128 * 32];
  const int tid = threadIdx.x, lane = tid & 63, w = tid >> 6;
  const int bm = blockIdx.x * 128, bn = blockIdx.y * 128;
  const int wr = (w >> 1) * 64, wc = (w & 1) * 64;
  f32x4 acc[4][4];
#pragma unroll
  for (int i = 0; i < 4; ++i)
#pragma unroll
    for (int j = 0; j < 4; ++j) acc[i][j] = f32x4{0.f, 0.f, 0.f, 0.f};

  const int srow  = lane >> 2;
  const int scol8 = (lane & 3) * 8;

  for (int kt = 0; kt < K; kt += 32) {
    __syncthreads();
#pragma unroll
    for (int it = 0; it < 2; ++it) {
      int seg = w * 2 + it;
      int ar = bm + seg * 16 + srow;
      int br = bn + seg * 16 + srow;
      gload_lds16(A  + (size_t)ar * K + kt + scol8, (char*)As + seg * 1024 + lane * 16);
      gload_lds16(Bt + (size_t)br * K + kt + scol8, (char*)Bs + seg * 1024 + lane * 16);
    }
    __syncthreads();
    bf16x8 af[4], bfr[4];
#pragma unroll
    for (int i = 0; i < 4; ++i) {
      int mrow = wr + i * 16 + (lane & 15);
      af[i] = *reinterpret_cast<const bf16x8*>((const char*)As + mrow * 64 + (lane >> 4) * 16);
    }
#pragma unroll
    for (int j = 0; j < 4; ++j) {
      int nrow = wc + j * 16 + (lane & 15);
      bfr[j] = *reinterpret_cast<const bf16x8*>((const char*)Bs + nrow * 64 + (lane >> 4) * 16);
    }
#pragma unroll
    for (int i = 0; i < 4; ++i)
#pragma unroll
      for (int j = 0; j < 4; ++j)
        acc[i][j] = __builtin_amdgcn_mfma_f32_16x16x32_bf16(af[i], bfr[j], acc[i][j], 0, 0, 0);
  }

#pragma unroll
  for (int i = 0; i < 4; ++i)
#pragma unroll
    for (int j = 0; j < 4; ++j)
#pragma unroll
      for (int r = 0; r < 4; ++r) {
        int mm = bm + wr + i * 16 + (lane >> 4) * 4 + r;
        int nn = bn + wc + j * 16 + (lane & 15);
        float val = acc[i][j][r];
        if (F32OUT)
          Cf[(size_t)mm * N + nn] = val + bias[nn];
        else
          Cb[(size_t)mm * N + nn] = (bf16_t)val;
      }
}

// ---------------- GEMM 64x128 ----------------
template <int F32OUT>
__global__ __launch_bounds__(256) void k_gemm64(const bf16_t* __restrict__ A,
                                                const bf16_t* __restrict__ Bt,
                                                bf16_t* __restrict__ Cb,
                                                float* __restrict__ Cf,
                                                const float* __restrict__ bias,
                                                int M, int N, int K) {
  __shared__ alignas(16) bf16_t As[64 * 32];
  __shared__ alignas(16) bf16_t Bs[128 * 32];
  const int tid = threadIdx.x, lane = tid & 63, w = tid >> 6;
  const int bm = blockIdx.x * 64, bn = blockIdx.y * 128;
  const int wr = (w >> 1) * 32, wc = (w & 1) * 64;
  f32x4 acc[2][4];
#pragma unroll
  for (int i = 0; i < 2; ++i)
#pragma unroll
    for (int j = 0; j < 4; ++j) acc[i][j] = f32x4{0.f, 0.f, 0.f, 0.f};

  const int srow  = lane >> 2;
  const int scol8 = (lane & 3) * 8;

  for (int kt = 0; kt < K; kt += 32) {
    __syncthreads();
#pragma unroll
    for (int it = 0; it < 3; ++it) {
      int s = w * 3 + it;
      if (s < 4)
        gload_lds16(A + (size_t)(bm + s * 16 + srow) * K + kt + scol8,
                    (char*)As + s * 1024 + lane * 16);
      else
        gload_lds16(Bt + (size_t)(bn + (s - 4) * 16 + srow) * K + kt + scol8,
                    (char*)Bs + (s - 4) * 1024 + lane * 16);
    }
    __syncthreads();
    bf16x8 af[2], bfr[4];
#pragma unroll
    for (int i = 0; i < 2; ++i) {
      int mrow = wr + i * 16 + (lane & 15);
      af[i] = *reinterpret_cast<const bf16x8*>((const char*)As + mrow * 64 + (lane >> 4) * 16);
    }
#pragma unroll
    for (int j = 0; j < 4; ++j) {
      int nrow = wc + j * 16 + (lane & 15);
      bfr[j] = *reinterpret_cast<const bf16x8*>((const char*)Bs + nrow * 64 + (lane >> 4) * 16);
    }
#pragma unroll
    for (int i = 0; i < 2; ++i)
#pragma unroll
      for (int j = 0; j < 4; ++j)
        acc[i][j] = __builtin_amdgcn_mfma_f32_16x16x32_bf16(af[i], bfr[j], acc[i][j], 0, 0, 0);
  }

#pragma unroll
  for (int i = 0; i < 2; ++i)
#pragma unroll
    for (int j = 0; j < 4; ++j)
#pragma unroll
      for (int r = 0; r < 4; ++r) {
        int mm = bm + wr + i * 16 + (lane >> 4) * 4 + r;
        int nn = bn + wc + j * 16 + (lane & 15);
        float val = acc[i][j][r];
        if (F32OUT)
          Cf[(size_t)mm * N + nn] = val + bias[nn];
        else
          Cb[(size_t)mm * N + nn] = (bf16_t)val;
      }
}

// ---------------- fused: RoPE (q scaled by 1/32) + V transpose ----------------
__global__ __launch_bounds__(256) void k_rope_vt(bf16_t* __restrict__ qkv,
                                                 const float* __restrict__ psin,
                                                 const float* __restrict__ pcos,
                                                 bf16_t* __restrict__ Vt) {
  __shared__ bf16_t tile[64][72];
  int b = blockIdx.x;
  if (b < NTOK - 1) {
    const int i = b + 1;
    const int t = threadIdx.x;
#pragma unroll
    for (int itr = 0; itr < 4; ++itr) {
      int pidx = itr * 256 + t;
      int half = pidx >> 9;              // 0=q, 1=k
      int pp   = pidx & 511;
      int hh = pp >> 5, tt2 = pp & 31;
      size_t off = (size_t)i * QKVN + half * 1024 + hh * 64 + tt2 * 2;
      float sn = psin[(size_t)(i - 1) * 32 + tt2];
      float cs = pcos[(size_t)(i - 1) * 32 + tt2];
      unsigned int u = *reinterpret_cast<const unsigned int*>(qkv + off);
      float x0 = bf2f(__builtin_bit_cast(bf16_t, (unsigned short)(u & 0xffffu)));
      float x1 = bf2f(__builtin_bit_cast(bf16_t, (unsigned short)(u >> 16)));
      const float mul = half ? 1.0f : 0.03125f;   // fold softmax scale into q (exact 2^-5)
      unsigned short b0 = __builtin_bit_cast(unsigned short, (bf16_t)((x0 * cs - x1 * sn) * mul));
      unsigned short b1 = __builtin_bit_cast(unsigned short, (bf16_t)((x1 * cs + x0 * sn) * mul));
      *reinterpret_cast<unsigned int*>(qkv + off) = (unsigned int)b0 | ((unsigned int)b1 << 16);
    }
  } else {
    b -= (NTOK - 1);
    const int n0 = (b & 31) * 64;
    const int h  = b >> 5;
    const int r  = threadIdx.x >> 2;
    const int cq = threadIdx.x & 3;
    const bf16_t* src = qkv + (size_t)(n0 + r) * QKVN + 2048 + h * DH + cq * 16;
    bf16x8 v0 = *reinterpret_cast<const bf16x8*>(src);
    bf16x8 v1 = *reinterpret_cast<const bf16x8*>(src + 8);
#pragma unroll
    for (int e = 0; e < 8; ++e) { tile[r][cq * 16 + e] = v0[e]; tile[r][cq * 16 + 8 + e] = v1[e]; }
    __syncthreads();
    const int d = r;
    bf16x8 o0, o1;
#pragma unroll
    for (int e = 0; e < 8; ++e) { o0[e] = tile[cq * 16 + e][d]; o1[e] = tile[cq * 16 + 8 + e][d]; }
    bf16_t* dst = Vt + ((size_t)h * DH + d) * NTOK + n0 + cq * 16;
    *reinterpret_cast<bf16x8*>(dst)     = o0;
    *reinterpret_cast<bf16x8*>(dst + 8) = o1;
  }
}

// ---------------- flash attention partials: 128 q-rows x <=512 keys, 8 waves ----------------
__global__ __launch_bounds__(512) void k_attn_part(const bf16_t* __restrict__ qkv,
                                                   const bf16_t* __restrict__ Vt,
                                                   const int* __restrict__ mask,
                                                   char* __restrict__ part) {
  __shared__ alignas(16) bf16_t Ks[2][64][64];   // 16 KB
  __shared__ alignas(16) bf16_t Vs[2][64][64];   // 16 KB
  __shared__ alignas(16) bf16_t Ps[8][1024];     // 16 KB
  __shared__ unsigned char padc[512];

  const int h = blockIdx.y;
  const int slot = (SLOTS_PER_HEAD - 1) - blockIdx.x;   // heavy slots first
  int g;
  if (slot < 4) g = 0; else if (slot < 12) g = 1; else if (slot < 24) g = 2; else g = 3;
  const int tt = slot - 2 * g * (g + 1);
  const int Q = (g << 2) + tt / (g + 1);
  const int c = tt - (tt / (g + 1)) * (g + 1);
  const int q0 = Q * 128;
  const int kbeg = c * 512;
  const int kvlen = (Q + 1) * 128;
  const int klen = min(512, kvlen - kbeg);
  const int ntiles = klen >> 6;                 // 2,4,6,8

  const int tid = threadIdx.x, lane = tid & 63, w = tid >> 6;

  for (int jr = tid; jr < klen; jr += 512) {
    int j = kbeg + jr;
    padc[jr] = (j == 0) ? 1 : (unsigned char)(mask[j - 1] != 0);
  }

  const int iw = q0 + w * 16;                   // wave's first q-row
  bf16x8 qf[2];
  {
    const bf16_t* qp = qkv + (size_t)(iw + (lane & 15)) * QKVN + h * DH + (lane >> 4) * 8;
    qf[0] = *reinterpret_cast<const bf16x8*>(qp);
    qf[1] = *reinterpret_cast<const bf16x8*>(qp + 32);
  }
  bf16x8 ones;
#pragma unroll
  for (int e = 0; e < 8; ++e) ones[e] = (bf16_t)1.0f;

  float m_run[4], m2[4];
  f32x4 acc[4], accl;
#pragma unroll
  for (int r = 0; r < 4; ++r) { m_run[r] = -1e30f; m2[r] = -1e30f; }
#pragma unroll
  for (int df = 0; df < 4; ++df) acc[df] = f32x4{0.f, 0.f, 0.f, 0.f};
  accl = f32x4{0.f, 0.f, 0.f, 0.f};

  const int r8 = lane >> 3;
  const int sw = (lane & 7) ^ r8;

  // staging: 16 segs (0..7 K-rows, 8..15 V-rows); wave w stages segs 2w, 2w+1
#define STAGE(KB, BUF)                                                                   \
  {                                                                                      \
    _Pragma("unroll") for (int i2 = 0; i2 < 2; ++i2) {                                   \
      int s = w * 2 + i2;                                                                \
      if (s < 8) {                                                                       \
        int row = s * 8 + r8;                                                            \
        gload_lds16(qkv + (size_t)((KB) + row) * QKVN + DIM + h * DH + sw * 8,           \
                    (char*)Ks + (BUF)*8192 + s * 1024 + lane * 16);                      \
      } else {                                                                           \
        int row = (s - 8) * 8 + r8;                                                      \
        gload_lds16(Vt + ((size_t)h * DH + row) * NTOK + (KB) + sw * 8,                  \
                    (char*)Vs + (BUF)*8192 + (s - 8) * 1024 + lane * 16);                \
      }                                                                                  \
    }                                                                                    \
  }

  STAGE(kbeg, 0)

  for (int it = 0; it < ntiles; ++it) {
    const int buf = it & 1;
    if (it + 1 < ntiles) {
      STAGE(kbeg + (it + 1) * 64, buf ^ 1)
      asm volatile("s_waitcnt vmcnt(2)" ::: "memory");
    } else {
      asm volatile("s_waitcnt vmcnt(0)" ::: "memory");
    }
    __builtin_amdgcn_s_barrier();

    const int k0 = kbeg + it * 64;
    if (k0 <= iw + 15) {   // live tile for this wave
      const char* KsT = (const char*)Ks + buf * 8192;
      const char* VsT = (const char*)Vs + buf * 8192;

      f32x4 sfr[4];
      __builtin_amdgcn_s_setprio(1);
#pragma unroll
      for (int jf = 0; jf < 4; ++jf) {
        f32x4 s = f32x4{0.f, 0.f, 0.f, 0.f};
        int jl = jf * 16 + (lane & 15);
#pragma unroll
        for (int ks = 0; ks < 2; ++ks) {
          int inrow = (ks * 64 + (lane >> 4) * 16) ^ ((jl & 7) << 4);
          bf16x8 kf = *reinterpret_cast<const bf16x8*>(KsT + jl * 128 + inrow);
          s = __builtin_amdgcn_mfma_f32_16x16x32_bf16(qf[ks], kf, s, 0, 0, 0);
        }
        sfr[jf] = s;
      }
      __builtin_amdgcn_s_setprio(0);

      // local max (raw scores; masked entries may inflate m harmlessly)
      float pmax[4] = {-3e38f, -3e38f, -3e38f, -3e38f};
#pragma unroll
      for (int jf = 0; jf < 4; ++jf)
#pragma unroll
        for (int r = 0; r < 4; ++r) pmax[r] = fmaxf(pmax[r], sfr[jf][r]);

      int dok = (pmax[0] <= m_run[0] + 8.f) && (pmax[1] <= m_run[1] + 8.f) &&
                (pmax[2] <= m_run[2] + 8.f) && (pmax[3] <= m_run[3] + 8.f);
      if (!__all(dok)) {
#pragma unroll
        for (int o = 1; o < 16; o <<= 1)
#pragma unroll
          for (int r = 0; r < 4; ++r) pmax[r] = fmaxf(pmax[r], __shfl_xor(pmax[r], o, 64));
#pragma unroll
        for (int r = 0; r < 4; ++r) {
          float mnew = fmaxf(m_run[r], pmax[r]);
          float corr = __builtin_amdgcn_exp2f((m_run[r] - mnew) * L2E);
          m_run[r] = mnew;
          m2[r] = mnew * L2E;
          accl[r] *= corr;
#pragma unroll
          for (int df = 0; df < 4; ++df) acc[df][r] *= corr;
        }
      }

      const bool needC = (k0 + 63 > iw);
#pragma unroll
      for (int jf = 0; jf < 4; ++jf) {
        int jl = jf * 16 + (lane & 15);
        int j = k0 + jl;
        bool padj = padc[j - kbeg] != 0;
#pragma unroll
        for (int r = 0; r < 4; ++r) {
          float pe = __builtin_amdgcn_exp2f(__builtin_fmaf(sfr[jf][r], L2E, -m2[r]));
          bool ok = padj;
          if (needC) ok = ok && (j <= iw + (lane >> 4) * 4 + r);
          pe = ok ? pe : 0.f;
          int m = (lane >> 4) * 4 + r;
          *reinterpret_cast<bf16_t*>((char*)&Ps[w][0] + m * 128 + ((jl * 2) ^ ((m & 7) << 4))) =
              (bf16_t)pe;
        }
      }

      // O += P V ; l += P 1 (ones-column)
      __builtin_amdgcn_s_setprio(1);
#pragma unroll
      for (int ks = 0; ks < 2; ++ks) {
        int mm = lane & 15;
        int inrow = (ks * 64 + (lane >> 4) * 16) ^ ((mm & 7) << 4);
        bf16x8 pa = *reinterpret_cast<const bf16x8*>((const char*)&Ps[w][0] + mm * 128 + inrow);
        accl = __builtin_amdgcn_mfma_f32_16x16x32_bf16(pa, ones, accl, 0, 0, 0);
#pragma unroll
        for (int df = 0; df < 4; ++df) {
          int d = df * 16 + (lane & 15);
          int vin = (ks * 64 + (lane >> 4) * 16) ^ ((d & 7) << 4);
          bf16x8 vf = *reinterpret_cast<const bf16x8*>(VsT + d * 128 + vin);
          acc[df] = __builtin_amdgcn_mfma_f32_16x16x32_bf16(pa, vf, acc[df], 0, 0, 0);
        }
      }
      __builtin_amdgcn_s_setprio(0);
    }
    __builtin_amdgcn_s_barrier();
  }
#undef STAGE

  char* pb = part + (size_t)(h * SLOTS_PER_HEAD + slot) * PART_STRIDE;
  bf16_t* po = (bf16_t*)pb;
  float* pm = (float*)(pb + 16384);
  float* pl = (float*)(pb + 16896);
#pragma unroll
  for (int df = 0; df < 4; ++df)
#pragma unroll
    for (int r = 0; r < 4; ++r) {
      int row = w * 16 + (lane >> 4) * 4 + r;
      po[row * 64 + df * 16 + (lane & 15)] = (bf16_t)acc[df][r];
    }
  if ((lane & 15) == 0) {
#pragma unroll
    for (int r = 0; r < 4; ++r) {
      int row = w * 16 + (lane >> 4) * 4 + r;
      pm[row] = m2[r];       // log2 units
      pl[row] = accl[r];
    }
  }
}

// ---------------- merge partials -> Ob ----------------
// grid (16, 16): block = (Q, head). thread owns (row = t>>1, 32 dims).
__global__ __launch_bounds__(256) void k_merge(const char* __restrict__ part,
                                               bf16_t* __restrict__ Ob) {
  const int Q = blockIdx.x, h = blockIdx.y;
  const int g = Q >> 2, nch = g + 1;
  const int cum = 2 * g * (g + 1) + (Q & 3) * nch;
  const int t = threadIdx.x;
  const int row = t >> 1, half = t & 1;

  float acc[32];
#pragma unroll
  for (int e = 0; e < 32; ++e) acc[e] = 0.f;
  float M = -3e38f, L = 0.f;

  for (int c = 0; c < nch; ++c) {
    const char* pb = part + (size_t)(h * SLOTS_PER_HEAD + cum + c) * PART_STRIDE;
    float mc = ((const float*)(pb + 16384))[row];
    float lc = ((const float*)(pb + 16896))[row];
    float Mn = fmaxf(M, mc);
    float sOld = __builtin_amdgcn_exp2f(M - Mn), sNew = __builtin_amdgcn_exp2f(mc - Mn);
    M = Mn;
    L = L * sOld + lc * sNew;
    const bf16_t* od = (const bf16_t*)pb + row * 64 + half * 32;
#pragma unroll
    for (int e4 = 0; e4 < 4; ++e4) {
      bf16x8 o8 = *reinterpret_cast<const bf16x8*>(od + e4 * 8);
#pragma unroll
      for (int e = 0; e < 8; ++e)
        acc[e4 * 8 + e] = acc[e4 * 8 + e] * sOld + (float)o8[e] * sNew;
    }
  }
  const float inv = 1.0f / L;
  bf16_t* dst = Ob + (size_t)(Q * 128 + row) * DIM + h * DH + half * 32;
#pragma unroll
  for (int e4 = 0; e4 < 4; ++e4) {
    bf16x8 r8o;
#pragma unroll
    for (int e = 0; e < 8; ++e) r8o[e] = (bf16_t)(acc[e4 * 8 + e] * inv);
    *reinterpret_cast<bf16x8*>(dst + e4 * 8) = r8o;
  }
}

// ---------------- row 0 (non-causal: attends all keys) ----------------
__global__ __launch_bounds__(256) void k_row0(const bf16_t* __restrict__ qkv,
                                              const bf16_t* __restrict__ Vt,
                                              const int* __restrict__ mask,
                                              bf16_t* __restrict__ Ob) {
  __shared__ float qv[64];
  __shared__ float sbuf[2048];
  __shared__ float red[4];
  __shared__ float red2[4][64];
  const int h = blockIdx.x, t = threadIdx.x, lane = t & 63, w = t >> 6;
  if (t < 64) qv[t] = (float)qkv[h * DH + t];   // row 0 q, un-roped & un-scaled
  __syncthreads();

  float sm[8];
  float lmax = -1e30f;
#pragma unroll
  for (int p = 0; p < 8; ++p) {
    int j = p * 256 + t;
    const bf16_t* kr = qkv + (size_t)j * QKVN + DIM + h * DH;
    float s = 0.f;
#pragma unroll
    for (int u = 0; u < 8; ++u) {
      bf16x8 kv8 = *reinterpret_cast<const bf16x8*>(kr + u * 8);
#pragma unroll
      for (int e = 0; e < 8; ++e) s += qv[u * 8 + e] * (float)kv8[e];
    }
    bool padj = (j == 0) || (mask[j - 1] != 0);
    s = padj ? s * 0.03125f : -1e30f;
    sm[p] = s;
    lmax = fmaxf(lmax, s);
  }
#pragma unroll
  for (int o = 1; o < 64; o <<= 1) lmax = fmaxf(lmax, __shfl_xor(lmax, o, 64));
  if (lane == 0) red[w] = lmax;
  __syncthreads();
  const float M = fmaxf(fmaxf(red[0], red[1]), fmaxf(red[2], red[3]));
  float ls = 0.f;
#pragma unroll
  for (int p = 0; p < 8; ++p) {
    float pe = __expf(sm[p] - M);
    sbuf[p * 256 + t] = pe;
    ls += pe;
  }
#pragma unroll
  for (int o = 1; o < 64; o <<= 1) ls += __shfl_xor(ls, o, 64);
  __syncthreads();
  if (lane == 0) red[w] = ls;
  __syncthreads();
  const float L = red[0] + red[1] + red[2] + red[3];

  const int d = t & 63, qr = t >> 6;
  const bf16_t* vr = Vt + ((size_t)h * DH + d) * NTOK + qr * 512;
  float a = 0.f;
#pragma unroll 8
  for (int u = 0; u < 64; ++u) {
    bf16x8 v8 = *reinterpret_cast<const bf16x8*>(vr + u * 8);
#pragma unroll
    for (int e = 0; e < 8; ++e) a += sbuf[qr * 512 + u * 8 + e] * (float)v8[e];
  }
  red2[qr][d] = a;
  __syncthreads();
  if (t < 64) {
    float o = (red2[0][t] + red2[1][t] + red2[2][t] + red2[3][t]) / L;
    Ob[h * DH + t] = (bf16_t)o;
  }
}

// ---------------- host ----------------
extern "C" void kernel_launch(void* const* d_in, const int* in_sizes, int n_in,
                              void* d_out, int out_size, void* d_ws, size_t ws_size,
                              hipStream_t stream) {
  const float* x       = (const float*)d_in[0];
  const float* pos_sin = (const float*)d_in[1];
  const float* pos_cos = (const float*)d_in[2];
  const int*   mask    = (const int*)d_in[3];
  const float* ln_s    = (const float*)d_in[4];
  const float* ln_b    = (const float*)d_in[5];
  const float* w_qkv   = (const float*)d_in[6];
  const float* w_out   = (const float*)d_in[7];
  const float* b_out   = (const float*)d_in[8];
  float* out = (float*)d_out;

  if (ws_size < 33554432u) return;

  char* ws = (char*)d_ws;
  bf16_t* qkv  = (bf16_t*)(ws + 0);           // 12 MiB
  bf16_t* Vt   = (bf16_t*)(ws + 12582912);    //  4 MiB
  bf16_t* Ob   = (bf16_t*)(ws + 16777216);    //  4 MiB
  char*   part = ws + 20971520;               // 10.63 MiB (16*40*17408)
  bf16_t* xn   = (bf16_t*)(ws + 20971520);    //  4 MiB, dead before part written
  bf16_t* Wqt  = (bf16_t*)(ws + 25165824);    //  6 MiB, dead before part written
  bf16_t* Wot  = (bf16_t*)(ws + 20971520);    //  2 MiB, written after merge (part dead)

  k_ln_tc<<<NTOK + 768, 256, 0, stream>>>(x, ln_s, ln_b, xn, w_qkv, Wqt);
  k_gemm_bt<0><<<dim3(16, 24), 256, 0, stream>>>(xn, Wqt, qkv, nullptr, nullptr,
                                                 NTOK, QKVN, DIM);
  k_rope_vt<<<(NTOK - 1) + 512, 256, 0, stream>>>(qkv, pos_sin, pos_cos, Vt);
  k_attn_part<<<dim3(SLOTS_PER_HEAD, NH), 512, 0, stream>>>(qkv, Vt, mask, part);
  k_merge<<<dim3(16, 16), 256, 0, stream>>>(part, Ob);
  k_tc<<<dim3(16, 16), 256, 0, stream>>>(w_out, Wot, 1024, 1024);
  k_row0<<<NH, 256, 0, stream>>>(qkv, Vt, mask, Ob);
  k_gemm64<1><<<dim3(32, 8), 256, 0, stream>>>(Ob, Wot, nullptr, out, b_out,
                                               NTOK, DIM, DIM);
}